// Round 1
// baseline (20720.441 us; speedup 1.0000x reference)
//
#include <hip/hip_runtime.h>
#include <math.h>

#define NN 50000
#define TT 12
#define EE 1600000
#define FF 16
#define HH 128
#define MT 128
#define GB 391  // ceil(NN/MT)

__device__ __forceinline__ float sigmoidf_(float x) { return 1.0f / (1.0f + expf(-x)); }

// ---------------------------------------------------------------------------
// P0: detect mask dtype. uint8: nonzero bytes at idx%4==1. int32: nonzero only
// at %4==0. float32 (1.0f = 00 00 80 3F): nonzero only at %4 in {2,3}.
__global__ void detect_mask(const unsigned char* __restrict__ m, int* __restrict__ flag) {
    __shared__ int cnt[2];
    if (threadIdx.x < 2) cnt[threadIdx.x] = 0;
    __syncthreads();
    int a = 0, b = 0;
    for (int base = 0; base < 4096; base += 256) {
        int idx = base + threadIdx.x;
        unsigned char v = m[idx];
        int r = idx & 3;
        if (v) { if (r == 0) a++; else if (r == 1) b++; }
    }
    atomicAdd(&cnt[0], a);
    atomicAdd(&cnt[1], b);
    __syncthreads();
    if (threadIdx.x == 0) flag[0] = cnt[1] > 0 ? 0 : (cnt[0] > 0 ? 1 : 2);
}

// P1: build hm[t][n] = mask & seen-before, mc[t][n] = mask
__global__ void build_masks(const void* __restrict__ mask, const int* __restrict__ flag,
                            unsigned char* __restrict__ hm, unsigned char* __restrict__ mc) {
    int n = blockIdx.x * 256 + threadIdx.x;
    if (n >= NN) return;
    int mode = flag[0];
    bool seen = false;
    for (int t = 0; t < TT; t++) {
        int idx = t * NN + n;
        bool m;
        if (mode == 0)      m = ((const unsigned char*)mask)[idx] != 0;
        else if (mode == 1) m = ((const int*)mask)[idx] != 0;
        else                m = ((const float*)mask)[idx] != 0.0f;
        hm[idx] = (m && seen) ? 1 : 0;
        mc[idx] = m ? 1 : 0;
        seen = seen || m;
    }
}

// P2: deg accumulation (deg buffer pre-zeroed; self-loop +1 added in dinv pass)
__global__ void deg_kernel(const int* __restrict__ ei, const float* __restrict__ ea,
                           float* __restrict__ deg) {
    int e = blockIdx.x * 256 + threadIdx.x;
    int t = blockIdx.y;
    int d = ei[(size_t)(2 * t + 1) * EE + e];
    float w = ea[(size_t)t * EE + e];
    atomicAdd(&deg[t * NN + d], w);
}

// P3: dinv = rsqrt(1 + deg), in place
__global__ void dinv_kernel(float* __restrict__ dinv) {
    int i = blockIdx.x * 256 + threadIdx.x;
    if (i >= TT * NN) return;
    dinv[i] = rsqrtf(1.0f + dinv[i]);
}

// P4: xagg[t][d][f] += norm * x[t][s][f]   (xagg pre-zeroed)
__global__ void xagg_kernel(const int* __restrict__ ei, const float* __restrict__ ea,
                            const float* __restrict__ x, const float* __restrict__ dinv,
                            float* __restrict__ xagg) {
    int e = blockIdx.x * 256 + threadIdx.x;
    int t = blockIdx.y;
    int s = ei[(size_t)(2 * t) * EE + e];
    int d = ei[(size_t)(2 * t + 1) * EE + e];
    float wv = ea[(size_t)t * EE + e];
    float nm = dinv[t * NN + s] * wv * dinv[t * NN + d];
    const float4* xr = (const float4*)(x + ((size_t)t * NN + s) * FF);
    float* o = xagg + ((size_t)t * NN + d) * FF;
#pragma unroll
    for (int q = 0; q < 4; q++) {
        float4 v = xr[q];
        atomicAdd(o + 4 * q + 0, nm * v.x);
        atomicAdd(o + 4 * q + 1, nm * v.y);
        atomicAdd(o + 4 * q + 2, nm * v.z);
        atomicAdd(o + 4 * q + 3, nm * v.w);
    }
}

// P5: self-loop: xagg[t][n][f] += x[t][n][f] * dinv^2
__global__ void self_kernel(const float* __restrict__ x, const float* __restrict__ dinv,
                            float* __restrict__ xagg) {
    int gid = blockIdx.x * 256 + threadIdx.x;  // over TT*NN*4 float4s
    if (gid >= TT * NN * 4) return;
    int tn = gid >> 2;
    float sn = dinv[tn] * dinv[tn];
    float4 xv = ((const float4*)x)[gid];
    float4* o = ((float4*)xagg) + gid;
    float4 v = *o;
    v.x += xv.x * sn; v.y += xv.y * sn; v.z += xv.z * sn; v.w += xv.w * sn;
    *o = v;
}

// P6: Weff[g] = Wc[g] @ Wl[g][0:128,:], beff[g] = bc[g] @ Wl_top + bl[g]
__global__ void weight_kernel(const float* Wc0, const float* bc0, const float* Wl0, const float* bl0,
                              const float* Wc1, const float* bc1, const float* Wl1, const float* bl1,
                              const float* Wc2, const float* bc2, const float* Wl2, const float* bl2,
                              float* __restrict__ Weff, float* __restrict__ beff) {
    __shared__ float WcS[FF][HH];
    int g = blockIdx.x;
    int j = threadIdx.x;  // 128 threads
    const float* Wc = g == 0 ? Wc0 : (g == 1 ? Wc1 : Wc2);
    const float* bc = g == 0 ? bc0 : (g == 1 ? bc1 : bc2);
    const float* Wl = g == 0 ? Wl0 : (g == 1 ? Wl1 : Wl2);
    const float* bl = g == 0 ? bl0 : (g == 1 ? bl1 : bl2);
    for (int q = 0; q < FF; q++) WcS[q][j] = Wc[q * HH + j];
    __syncthreads();
    float acc[FF];
#pragma unroll
    for (int i = 0; i < FF; i++) acc[i] = 0.0f;
    float accb = 0.0f;
    for (int k = 0; k < HH; k++) {
        float wl = Wl[k * HH + j];
        accb += bc[k] * wl;
#pragma unroll
        for (int i = 0; i < FF; i++) acc[i] += WcS[i][k] * wl;
    }
#pragma unroll
    for (int i = 0; i < FF; i++) Weff[(g * FF + i) * HH + j] = acc[i];
    beff[g * HH + j] = bl[j] + accb;
}

// C1: hp[n][:] = hm[n] ? h_state[n][:] : 0
__global__ void prep_hp(const float* __restrict__ hstate, const unsigned char* __restrict__ hm,
                        float* __restrict__ hp) {
    int gid = blockIdx.x * 256 + threadIdx.x;  // over NN*32 float4s (exact: 6250 blocks)
    int n = gid >> 5;
    float4 v = make_float4(0, 0, 0, 0);
    if (hm[n]) v = ((const float4*)hstate)[gid];
    ((float4*)hp)[gid] = v;
}

// G1: z/r gate GEMM. C[128 x 128] tile per block, K = 16 (xagg@Weff) + 128 (hp@Wl_bot).
// gate = blockIdx.y (0=z, 1=r). sigmoid epilogue.
__launch_bounds__(256)
__global__ void zr_gemm(const float* __restrict__ xagg, const float* __restrict__ hp,
                        const float* __restrict__ Weff, const float* __restrict__ beff,
                        const float* __restrict__ Wl0, const float* __restrict__ Wl1,
                        float* __restrict__ zbuf, float* __restrict__ rbuf) {
    __shared__ float As[16][MT + 2];
    __shared__ float Bs[16][132];
    const int tid = threadIdx.x;
    const int ty = tid >> 4;
    const int tx = tid & 15;
    const int m0 = blockIdx.x * MT;
    const int g = blockIdx.y;
    const float* Wl = g ? Wl1 : Wl0;
    const float* We = Weff + g * FF * HH;
    const float* be = beff + g * HH;
    float* ob = g ? rbuf : zbuf;

    float acc[8][8];
#pragma unroll
    for (int i = 0; i < 8; i++)
#pragma unroll
        for (int j = 0; j < 8; j++) acc[i][j] = 0.0f;

    const int arow = tid >> 1;
    const int ak0 = (tid & 1) * 8;
    const int bkk = tid >> 4;
    const int bc0 = (tid & 15) * 8;

    for (int ch = 0; ch < 9; ++ch) {
        float4 a0 = make_float4(0, 0, 0, 0), a1 = make_float4(0, 0, 0, 0);
        const int grow = m0 + arow;
        if (grow < NN) {
            const float* base = (ch == 0) ? (xagg + (size_t)grow * FF + ak0)
                                          : (hp + (size_t)grow * HH + (ch - 1) * 16 + ak0);
            a0 = *(const float4*)(base);
            a1 = *(const float4*)(base + 4);
        }
        const float* bsrc = (ch == 0) ? (We + bkk * HH + bc0)
                                      : (Wl + (size_t)(HH + (ch - 1) * 16 + bkk) * HH + bc0);
        float4 b0 = *(const float4*)(bsrc);
        float4 b1 = *(const float4*)(bsrc + 4);
        __syncthreads();  // previous iteration's compute done
        As[ak0 + 0][arow] = a0.x; As[ak0 + 1][arow] = a0.y;
        As[ak0 + 2][arow] = a0.z; As[ak0 + 3][arow] = a0.w;
        As[ak0 + 4][arow] = a1.x; As[ak0 + 5][arow] = a1.y;
        As[ak0 + 6][arow] = a1.z; As[ak0 + 7][arow] = a1.w;
        *(float4*)&Bs[bkk][bc0] = b0;
        *(float4*)&Bs[bkk][bc0 + 4] = b1;
        __syncthreads();
#pragma unroll
        for (int kk = 0; kk < 16; kk++) {
            float a[8], b[8];
#pragma unroll
            for (int i = 0; i < 4; i++) {
                float2 t2 = *(const float2*)&As[kk][32 * i + 2 * ty];
                a[2 * i] = t2.x; a[2 * i + 1] = t2.y;
            }
#pragma unroll
            for (int j = 0; j < 4; j++) {
                float2 t2 = *(const float2*)&Bs[kk][32 * j + 2 * tx];
                b[2 * j] = t2.x; b[2 * j + 1] = t2.y;
            }
#pragma unroll
            for (int i = 0; i < 8; i++)
#pragma unroll
                for (int j = 0; j < 8; j++) acc[i][j] += a[i] * b[j];
        }
    }
#pragma unroll
    for (int i = 0; i < 4; i++)
#pragma unroll
        for (int ii = 0; ii < 2; ii++) {
            const int row = 32 * i + 2 * ty + ii;
            const int grow = m0 + row;
            if (grow < NN) {
#pragma unroll
                for (int j = 0; j < 4; j++) {
                    const int c0 = 32 * j + 2 * tx;
                    float2 bb = *(const float2*)&be[c0];
                    float2 v;
                    v.x = sigmoidf_(acc[2 * i + ii][2 * j + 0] + bb.x);
                    v.y = sigmoidf_(acc[2 * i + ii][2 * j + 1] + bb.y);
                    *(float2*)&ob[(size_t)grow * HH + c0] = v;
                }
            }
        }
}

// G2: h gate GEMM. A(phase2) = hp*r fused at staging. Epilogue: h_new = z*hp+(1-z)*tanh(.)
// mcmask != null (cell mode): conditional store to outb (=h_state).
// mcmask == null (horizon): unconditional store to outb (=hp).
__launch_bounds__(256)
__global__ void h_gemm(const float* __restrict__ xagg, const float* __restrict__ hp,
                       const float* __restrict__ rbuf, const float* __restrict__ zbuf,
                       const float* __restrict__ Weff, const float* __restrict__ beff,
                       const float* __restrict__ Wl2, float* __restrict__ outb,
                       const unsigned char* __restrict__ mcmask) {
    __shared__ float As[16][MT + 2];
    __shared__ float Bs[16][132];
    const int tid = threadIdx.x;
    const int ty = tid >> 4;
    const int tx = tid & 15;
    const int m0 = blockIdx.x * MT;
    const float* We = Weff + 2 * FF * HH;
    const float* be = beff + 2 * HH;

    float acc[8][8];
#pragma unroll
    for (int i = 0; i < 8; i++)
#pragma unroll
        for (int j = 0; j < 8; j++) acc[i][j] = 0.0f;

    const int arow = tid >> 1;
    const int ak0 = (tid & 1) * 8;
    const int bkk = tid >> 4;
    const int bc0 = (tid & 15) * 8;

    for (int ch = 0; ch < 9; ++ch) {
        float4 a0 = make_float4(0, 0, 0, 0), a1 = make_float4(0, 0, 0, 0);
        const int grow = m0 + arow;
        if (grow < NN) {
            if (ch == 0) {
                const float* base = xagg + (size_t)grow * FF + ak0;
                a0 = *(const float4*)(base);
                a1 = *(const float4*)(base + 4);
            } else {
                const float* bh = hp + (size_t)grow * HH + (ch - 1) * 16 + ak0;
                const float* br = rbuf + (size_t)grow * HH + (ch - 1) * 16 + ak0;
                float4 h0 = *(const float4*)(bh), h1 = *(const float4*)(bh + 4);
                float4 r0 = *(const float4*)(br), r1 = *(const float4*)(br + 4);
                a0.x = h0.x * r0.x; a0.y = h0.y * r0.y; a0.z = h0.z * r0.z; a0.w = h0.w * r0.w;
                a1.x = h1.x * r1.x; a1.y = h1.y * r1.y; a1.z = h1.z * r1.z; a1.w = h1.w * r1.w;
            }
        }
        const float* bsrc = (ch == 0) ? (We + bkk * HH + bc0)
                                      : (Wl2 + (size_t)(HH + (ch - 1) * 16 + bkk) * HH + bc0);
        float4 b0 = *(const float4*)(bsrc);
        float4 b1 = *(const float4*)(bsrc + 4);
        __syncthreads();
        As[ak0 + 0][arow] = a0.x; As[ak0 + 1][arow] = a0.y;
        As[ak0 + 2][arow] = a0.z; As[ak0 + 3][arow] = a0.w;
        As[ak0 + 4][arow] = a1.x; As[ak0 + 5][arow] = a1.y;
        As[ak0 + 6][arow] = a1.z; As[ak0 + 7][arow] = a1.w;
        *(float4*)&Bs[bkk][bc0] = b0;
        *(float4*)&Bs[bkk][bc0 + 4] = b1;
        __syncthreads();
#pragma unroll
        for (int kk = 0; kk < 16; kk++) {
            float a[8], b[8];
#pragma unroll
            for (int i = 0; i < 4; i++) {
                float2 t2 = *(const float2*)&As[kk][32 * i + 2 * ty];
                a[2 * i] = t2.x; a[2 * i + 1] = t2.y;
            }
#pragma unroll
            for (int j = 0; j < 4; j++) {
                float2 t2 = *(const float2*)&Bs[kk][32 * j + 2 * tx];
                b[2 * j] = t2.x; b[2 * j + 1] = t2.y;
            }
#pragma unroll
            for (int i = 0; i < 8; i++)
#pragma unroll
                for (int j = 0; j < 8; j++) acc[i][j] += a[i] * b[j];
        }
    }
#pragma unroll
    for (int i = 0; i < 4; i++)
#pragma unroll
        for (int ii = 0; ii < 2; ii++) {
            const int row = 32 * i + 2 * ty + ii;
            const int grow = m0 + row;
            if (grow < NN) {
                bool m = (mcmask != nullptr) ? (mcmask[grow] != 0) : true;
#pragma unroll
                for (int j = 0; j < 4; j++) {
                    const int c0 = 32 * j + 2 * tx;
                    float2 bb = *(const float2*)&be[c0];
                    float2 z2 = *(const float2*)&zbuf[(size_t)grow * HH + c0];
                    float2 h2 = *(const float2*)&hp[(size_t)grow * HH + c0];
                    float ht0 = tanhf(acc[2 * i + ii][2 * j + 0] + bb.x);
                    float ht1 = tanhf(acc[2 * i + ii][2 * j + 1] + bb.y);
                    float2 v;
                    v.x = z2.x * h2.x + (1.0f - z2.x) * ht0;
                    v.y = z2.y * h2.y + (1.0f - z2.y) * ht1;
                    if (m) *(float2*)&outb[(size_t)grow * HH + c0] = v;
                }
            }
        }
}

// C4: out[n][o] = hp[n][:] . head_W[:,o] + head_b[o]; one wave per node
__global__ void head_kernel(const float* __restrict__ hp, const float* __restrict__ headW,
                            const float* __restrict__ headb, float* __restrict__ out) {
    int node = (blockIdx.x * 256 + threadIdx.x) >> 6;
    int lane = threadIdx.x & 63;
    if (node >= NN) return;
    const float* h = hp + (size_t)node * HH;
    float h0 = h[lane], h1 = h[64 + lane];
    float s0 = h0 * headW[lane * 3 + 0] + h1 * headW[(64 + lane) * 3 + 0];
    float s1 = h0 * headW[lane * 3 + 1] + h1 * headW[(64 + lane) * 3 + 1];
    float s2 = h0 * headW[lane * 3 + 2] + h1 * headW[(64 + lane) * 3 + 2];
#pragma unroll
    for (int off = 32; off > 0; off >>= 1) {
        s0 += __shfl_down(s0, off);
        s1 += __shfl_down(s1, off);
        s2 += __shfl_down(s2, off);
    }
    if (lane == 0) {
        out[(size_t)node * 3 + 0] = s0 + headb[0];
        out[(size_t)node * 3 + 1] = s1 + headb[1];
        out[(size_t)node * 3 + 2] = s2 + headb[2];
    }
}

// C5a: zero horizon xagg cols 0..2
__global__ void zero3_kernel(float* __restrict__ xaggH) {
    int n = blockIdx.x * 256 + threadIdx.x;
    if (n >= NN) return;
    xaggH[(size_t)n * FF + 0] = 0.0f;
    xaggH[(size_t)n * FF + 1] = 0.0f;
    xaggH[(size_t)n * FF + 2] = 0.0f;
}

// C5b: scatter pred into horizon xagg cols 0..2
__global__ void predagg_kernel(const int* __restrict__ srcp, const int* __restrict__ dstp,
                               const float* __restrict__ ewp, const float* __restrict__ dinv11,
                               const float* __restrict__ pred, float* __restrict__ xaggH) {
    int e = blockIdx.x * 256 + threadIdx.x;
    int s = srcp[e], d = dstp[e];
    float nm = dinv11[s] * ewp[e] * dinv11[d];
    atomicAdd(&xaggH[(size_t)d * FF + 0], nm * pred[(size_t)s * 3 + 0]);
    atomicAdd(&xaggH[(size_t)d * FF + 1], nm * pred[(size_t)s * 3 + 1]);
    atomicAdd(&xaggH[(size_t)d * FF + 2], nm * pred[(size_t)s * 3 + 2]);
}

// C5c: self loop for pred cols
__global__ void selfadd_kernel(const float* __restrict__ pred, const float* __restrict__ dinv11,
                               float* __restrict__ xaggH) {
    int n = blockIdx.x * 256 + threadIdx.x;
    if (n >= NN) return;
    float sn = dinv11[n] * dinv11[n];
    xaggH[(size_t)n * FF + 0] += pred[(size_t)n * 3 + 0] * sn;
    xaggH[(size_t)n * FF + 1] += pred[(size_t)n * 3 + 1] * sn;
    xaggH[(size_t)n * FF + 2] += pred[(size_t)n * 3 + 2] * sn;
}

extern "C" void kernel_launch(void* const* d_in, const int* in_sizes, int n_in,
                              void* d_out, int out_size, void* d_ws, size_t ws_size,
                              hipStream_t stream) {
    const float* x = (const float*)d_in[0];
    const int* ei = (const int*)d_in[1];
    const float* ea = (const float*)d_in[2];
    const void* mask = d_in[3];
    const float* Wc[3] = {(const float*)d_in[4], (const float*)d_in[8], (const float*)d_in[12]};
    const float* bc[3] = {(const float*)d_in[5], (const float*)d_in[9], (const float*)d_in[13]};
    const float* Wl[3] = {(const float*)d_in[6], (const float*)d_in[10], (const float*)d_in[14]};
    const float* bl[3] = {(const float*)d_in[7], (const float*)d_in[11], (const float*)d_in[15]};
    const float* headW = (const float*)d_in[16];
    const float* headb = (const float*)d_in[17];
    float* out = (float*)d_out;

    char* w = (char*)d_ws;
    auto alloc = [&](size_t bytes) {
        char* p = w;
        w += (bytes + 255) & ~(size_t)255;
        return p;
    };
    float* dinv = (float*)alloc((size_t)TT * NN * 4);
    float* xaggA = (float*)alloc((size_t)TT * NN * FF * 4);
    float* xaggH = (float*)alloc((size_t)NN * FF * 4);
    float* hstate = (float*)alloc((size_t)NN * HH * 4);
    float* hp = (float*)alloc((size_t)NN * HH * 4);
    float* zbuf = (float*)alloc((size_t)NN * HH * 4);
    float* rbuf = (float*)alloc((size_t)NN * HH * 4);
    float* Weff = (float*)alloc(3 * FF * HH * 4);
    float* beff = (float*)alloc(3 * HH * 4);
    unsigned char* hm = (unsigned char*)alloc((size_t)TT * NN);
    unsigned char* mc = (unsigned char*)alloc((size_t)TT * NN);
    int* flag = (int*)alloc(64);

    hipMemsetAsync(dinv, 0, (size_t)TT * NN * 4, stream);
    hipMemsetAsync(xaggA, 0, (size_t)TT * NN * FF * 4, stream);
    hipMemsetAsync(hstate, 0, (size_t)NN * HH * 4, stream);

    detect_mask<<<1, 256, 0, stream>>>((const unsigned char*)mask, flag);
    build_masks<<<(NN + 255) / 256, 256, 0, stream>>>(mask, flag, hm, mc);
    deg_kernel<<<dim3(EE / 256, TT), 256, 0, stream>>>(ei, ea, dinv);
    dinv_kernel<<<(TT * NN + 255) / 256, 256, 0, stream>>>(dinv);
    xagg_kernel<<<dim3(EE / 256, TT), 256, 0, stream>>>(ei, ea, x, dinv, xaggA);
    self_kernel<<<(TT * NN * 4 + 255) / 256, 256, 0, stream>>>(x, dinv, xaggA);
    weight_kernel<<<3, 128, 0, stream>>>(Wc[0], bc[0], Wl[0], bl[0],
                                         Wc[1], bc[1], Wl[1], bl[1],
                                         Wc[2], bc[2], Wl[2], bl[2], Weff, beff);

    // recurrent cells t = 0..11
    for (int t = 0; t < TT; t++) {
        prep_hp<<<NN * 32 / 256, 256, 0, stream>>>(hstate, hm + (size_t)t * NN, hp);
        zr_gemm<<<dim3(GB, 2), 256, 0, stream>>>(xaggA + (size_t)t * NN * FF, hp, Weff, beff,
                                                 Wl[0], Wl[1], zbuf, rbuf);
        h_gemm<<<GB, 256, 0, stream>>>(xaggA + (size_t)t * NN * FF, hp, rbuf, zbuf, Weff, beff,
                                       Wl[2], hstate, mc + (size_t)t * NN);
    }

    // horizon init: hp = mask[T-1] ? h_state : 0; xaggH = xagg(last graph, x_last)
    prep_hp<<<NN * 32 / 256, 256, 0, stream>>>(hstate, mc + (size_t)11 * NN, hp);
    hipMemcpyAsync(xaggH, xaggA + (size_t)11 * NN * FF, (size_t)NN * FF * 4,
                   hipMemcpyDeviceToDevice, stream);

    const int* src11 = ei + (size_t)22 * EE;
    const int* dst11 = ei + (size_t)23 * EE;
    const float* ew11 = ea + (size_t)11 * EE;
    const float* dinv11 = dinv + (size_t)11 * NN;

    for (int k = 0; k < 6; k++) {
        const float* xa = (k == 0) ? (xaggA + (size_t)11 * NN * FF) : xaggH;
        zr_gemm<<<dim3(GB, 2), 256, 0, stream>>>(xa, hp, Weff, beff, Wl[0], Wl[1], zbuf, rbuf);
        h_gemm<<<GB, 256, 0, stream>>>(xa, hp, rbuf, zbuf, Weff, beff, Wl[2], hp, nullptr);
        head_kernel<<<NN * 64 / 256, 256, 0, stream>>>(hp, headW, headb, out + (size_t)k * NN * 3);
        if (k < 5) {
            const float* pred = out + (size_t)k * NN * 3;
            zero3_kernel<<<(NN + 255) / 256, 256, 0, stream>>>(xaggH);
            predagg_kernel<<<EE / 256, 256, 0, stream>>>(src11, dst11, ew11, dinv11, pred, xaggH);
            selfadd_kernel<<<(NN + 255) / 256, 256, 0, stream>>>(pred, dinv11, xaggH);
        }
    }
}

// Round 2
// 5247.729 us; speedup vs baseline: 3.9485x; 3.9485x over previous
//
#include <hip/hip_runtime.h>
#include <math.h>

#define NN 50000
#define TT 12
#define EE 1600000
#define FF 16
#define HH 128
#define MT 128
#define GB 391      // ceil(NN/MT)
#define CHK 4096    // edges per partition chunk
#define NCH 391     // ceil(EE/CHK)
#define BINS 64     // padded bin count (63 used)
#define NBIN 63
#define BUCKET 800  // nodes per bin

__device__ __forceinline__ float sigmoidf_(float x) { return 1.0f / (1.0f + expf(-x)); }

// ---------------------------------------------------------------------------
// P0: detect mask dtype. uint8: nonzero bytes at idx%4==1. int32: nonzero only
// at %4==0. float32 (1.0f = 00 00 80 3F): nonzero only at %4 in {2,3}.
__global__ void detect_mask(const unsigned char* __restrict__ m, int* __restrict__ flag) {
    __shared__ int cnt[2];
    if (threadIdx.x < 2) cnt[threadIdx.x] = 0;
    __syncthreads();
    int a = 0, b = 0;
    for (int base = 0; base < 4096; base += 256) {
        int idx = base + threadIdx.x;
        unsigned char v = m[idx];
        int r = idx & 3;
        if (v) { if (r == 0) a++; else if (r == 1) b++; }
    }
    atomicAdd(&cnt[0], a);
    atomicAdd(&cnt[1], b);
    __syncthreads();
    if (threadIdx.x == 0) flag[0] = cnt[1] > 0 ? 0 : (cnt[0] > 0 ? 1 : 2);
}

// P1: build hm[t][n] = mask & seen-before, mc[t][n] = mask
__global__ void build_masks(const void* __restrict__ mask, const int* __restrict__ flag,
                            unsigned char* __restrict__ hm, unsigned char* __restrict__ mc) {
    int n = blockIdx.x * 256 + threadIdx.x;
    if (n >= NN) return;
    int mode = flag[0];
    bool seen = false;
    for (int t = 0; t < TT; t++) {
        int idx = t * NN + n;
        bool m;
        if (mode == 0)      m = ((const unsigned char*)mask)[idx] != 0;
        else if (mode == 1) m = ((const int*)mask)[idx] != 0;
        else                m = ((const float*)mask)[idx] != 0.0f;
        hm[idx] = (m && seen) ? 1 : 0;
        mc[idx] = m ? 1 : 0;
        seen = seen || m;
    }
}

// ---------------------------------------------------------------------------
// Graph partition pipeline: bin edges by dst/BUCKET, then LDS-local gather.
// Sorted slot remap: slot(t) = (t+1)%12 so t=11 lives in slot 0 (it must
// survive the recurrence for the horizon; slots 1..11 are reused as
// hstate/hp/zbuf/rbuf once the gathers are done).

// S1: per-chunk histogram of dst bins. chunkHist layout: [t][bin][chunk]
__global__ void hist_kernel(const int* __restrict__ ei, int* __restrict__ chunkHist) {
    __shared__ int h[BINS];
    int c = blockIdx.x, t = blockIdx.y, tid = threadIdx.x;
    if (tid < BINS) h[tid] = 0;
    __syncthreads();
    const int* dstp = ei + (size_t)(2 * t + 1) * EE;
    int e0 = c * CHK;
    for (int i = tid; i < CHK; i += 256) {
        int e = e0 + i;
        if (e < EE) atomicAdd(&h[dstp[e] / BUCKET], 1);
    }
    __syncthreads();
    if (tid < BINS) chunkHist[((size_t)t * BINS + tid) * NCH + c] = h[tid];
}

// S2: in-place exclusive scan of each t's [BINS*NCH] count array
__global__ void scan_kernel(int* __restrict__ buf) {
    __shared__ int ps[1024];
    const int L = BINS * NCH;        // 25024
    const int PER = 25;              // 1024*25 >= L
    int t = blockIdx.x, tid = threadIdx.x;
    int* a = buf + (size_t)t * L;
    int i0 = tid * PER, i1 = min(i0 + PER, L);
    int s = 0;
    for (int i = i0; i < i1; i++) s += a[i];
    ps[tid] = s;
    __syncthreads();
    for (int off = 1; off < 1024; off <<= 1) {
        int v = (tid >= off) ? ps[tid - off] : 0;
        __syncthreads();
        ps[tid] += v;
        __syncthreads();
    }
    int base = (tid == 0) ? 0 : ps[tid - 1];
    for (int i = i0; i < i1; i++) { int v = a[i]; a[i] = base; base += v; }
}

// S3: scatter edges into bin-sorted order. Packed: src | (dst_local<<17).
__global__ void scatter_kernel(const int* __restrict__ ei, const float* __restrict__ ea,
                               const int* __restrict__ chunkOff, float* __restrict__ PW) {
    __shared__ int cur[BINS];
    int c = blockIdx.x, t = blockIdx.y, tid = threadIdx.x;
    if (tid < BINS) cur[tid] = chunkOff[((size_t)t * BINS + tid) * NCH + c];
    __syncthreads();
    int sl = (t + 1) % 12;
    unsigned int* sp = (unsigned int*)PW + (size_t)sl * EE;
    float* sw = PW + (size_t)(12 + sl) * EE;
    const int* srcp = ei + (size_t)(2 * t) * EE;
    const int* dstp = ei + (size_t)(2 * t + 1) * EE;
    const float* wp = ea + (size_t)t * EE;
    int e0 = c * CHK;
    for (int i = tid; i < CHK; i += 256) {
        int e = e0 + i;
        if (e < EE) {
            int d = dstp[e];
            int b = d / BUCKET;
            int pos = atomicAdd(&cur[b], 1);
            sp[pos] = (unsigned int)srcp[e] | ((unsigned int)(d - b * BUCKET) << 17);
            sw[pos] = wp[e];
        }
    }
}

// S4: per-bin degree sum -> dinv = rsqrt(1 + deg)  (self-loop weight 1)
__global__ void degsort_kernel(const float* __restrict__ PW, const int* __restrict__ chunkOff,
                               float* __restrict__ dinvG) {
    __shared__ float dl[BUCKET];
    int b = blockIdx.x, t = blockIdx.y, tid = threadIdx.x;
    for (int i = tid; i < BUCKET; i += 256) dl[i] = 0.0f;
    __syncthreads();
    int sl = (t + 1) % 12;
    const unsigned int* sp = (const unsigned int*)PW + (size_t)sl * EE;
    const float* sw = PW + (size_t)(12 + sl) * EE;
    const int* off = chunkOff + (size_t)t * BINS * NCH;
    int e0 = off[b * NCH], e1 = off[(b + 1) * NCH];
    for (int e = e0 + tid; e < e1; e += 256) atomicAdd(&dl[sp[e] >> 17], sw[e]);
    __syncthreads();
    for (int i = tid; i < BUCKET; i += 256) {
        int n = b * BUCKET + i;
        if (n < NN) dinvG[(size_t)t * NN + n] = rsqrtf(1.0f + dl[i]);
    }
}

// S5: per-bin feature aggregation. agg stride 17 (16 would alias to 2 banks).
// xagg[t][d][f] = dinv_d * sum_e(dinv_s*w*x[s][f]) + dinv_d^2 * x[d][f]
__launch_bounds__(512)
__global__ void gather_kernel(const float* __restrict__ PW, const int* __restrict__ chunkOff,
                              const float* __restrict__ dinvG, const float* __restrict__ x,
                              float* __restrict__ xagg) {
    __shared__ float agg[BUCKET * 17];
    int b = blockIdx.x, t = blockIdx.y, tid = threadIdx.x;
    for (int i = tid; i < BUCKET * 17; i += 512) agg[i] = 0.0f;
    __syncthreads();
    int sl = (t + 1) % 12;
    const unsigned int* sp = (const unsigned int*)PW + (size_t)sl * EE;
    const float* sw = PW + (size_t)(12 + sl) * EE;
    const int* off = chunkOff + (size_t)t * BINS * NCH;
    const float* dv = dinvG + (size_t)t * NN;
    const float* xt = x + (size_t)t * NN * FF;
    int e0 = off[b * NCH], e1 = off[(b + 1) * NCH];
    for (int e = e0 + tid; e < e1; e += 512) {
        unsigned int p = sp[e];
        int s = p & 0x1FFFF;
        int dloc = p >> 17;
        float nm = sw[e] * dv[s];
        const float4* xr = (const float4*)(xt + (size_t)s * FF);
        float* ag = agg + dloc * 17;
        float4 v0 = xr[0], v1 = xr[1], v2 = xr[2], v3 = xr[3];
        atomicAdd(ag + 0,  nm * v0.x);  atomicAdd(ag + 1,  nm * v0.y);
        atomicAdd(ag + 2,  nm * v0.z);  atomicAdd(ag + 3,  nm * v0.w);
        atomicAdd(ag + 4,  nm * v1.x);  atomicAdd(ag + 5,  nm * v1.y);
        atomicAdd(ag + 6,  nm * v1.z);  atomicAdd(ag + 7,  nm * v1.w);
        atomicAdd(ag + 8,  nm * v2.x);  atomicAdd(ag + 9,  nm * v2.y);
        atomicAdd(ag + 10, nm * v2.z);  atomicAdd(ag + 11, nm * v2.w);
        atomicAdd(ag + 12, nm * v3.x);  atomicAdd(ag + 13, nm * v3.y);
        atomicAdd(ag + 14, nm * v3.z);  atomicAdd(ag + 15, nm * v3.w);
    }
    __syncthreads();
    for (int i = tid; i < BUCKET * FF; i += 512) {
        int nl = i >> 4, f = i & 15;
        int n = b * BUCKET + nl;
        if (n < NN) {
            float dd = dv[n];
            float xv = xt[(size_t)n * FF + f];
            xagg[((size_t)t * NN + n) * FF + f] = dd * agg[nl * 17 + f] + dd * dd * xv;
        }
    }
}

// S6 (horizon): 3-feature re-aggregation of pred over the t=11 graph
__global__ void gather3_kernel(const float* __restrict__ PW, const int* __restrict__ chunkOff,
                               const float* __restrict__ dinvG, const float* __restrict__ pred,
                               float* __restrict__ xaggH) {
    __shared__ float agg[BUCKET * 3];
    int b = blockIdx.x, tid = threadIdx.x;
    for (int i = tid; i < BUCKET * 3; i += 256) agg[i] = 0.0f;
    __syncthreads();
    const unsigned int* sp = (const unsigned int*)PW;            // slot 0 = t 11
    const float* sw = PW + (size_t)12 * EE;
    const int* off = chunkOff + (size_t)11 * BINS * NCH;
    const float* dv = dinvG + (size_t)11 * NN;
    int e0 = off[b * NCH], e1 = off[(b + 1) * NCH];
    for (int e = e0 + tid; e < e1; e += 256) {
        unsigned int p = sp[e];
        int s = p & 0x1FFFF;
        int dloc = p >> 17;
        float nm = sw[e] * dv[s];
        atomicAdd(&agg[dloc * 3 + 0], nm * pred[(size_t)s * 3 + 0]);
        atomicAdd(&agg[dloc * 3 + 1], nm * pred[(size_t)s * 3 + 1]);
        atomicAdd(&agg[dloc * 3 + 2], nm * pred[(size_t)s * 3 + 2]);
    }
    __syncthreads();
    for (int i = tid; i < BUCKET; i += 256) {
        int n = b * BUCKET + i;
        if (n < NN) {
            float dd = dv[n];
            xaggH[(size_t)n * FF + 0] = dd * agg[i * 3 + 0] + dd * dd * pred[(size_t)n * 3 + 0];
            xaggH[(size_t)n * FF + 1] = dd * agg[i * 3 + 1] + dd * dd * pred[(size_t)n * 3 + 1];
            xaggH[(size_t)n * FF + 2] = dd * agg[i * 3 + 2] + dd * dd * pred[(size_t)n * 3 + 2];
        }
    }
}

// ---------------------------------------------------------------------------
// P6: Weff[g] = Wc[g] @ Wl[g][0:128,:], beff[g] = bc[g] @ Wl_top + bl[g]
__global__ void weight_kernel(const float* Wc0, const float* bc0, const float* Wl0, const float* bl0,
                              const float* Wc1, const float* bc1, const float* Wl1, const float* bl1,
                              const float* Wc2, const float* bc2, const float* Wl2, const float* bl2,
                              float* __restrict__ Weff, float* __restrict__ beff) {
    __shared__ float WcS[FF][HH];
    int g = blockIdx.x;
    int j = threadIdx.x;  // 128 threads
    const float* Wc = g == 0 ? Wc0 : (g == 1 ? Wc1 : Wc2);
    const float* bc = g == 0 ? bc0 : (g == 1 ? bc1 : bc2);
    const float* Wl = g == 0 ? Wl0 : (g == 1 ? Wl1 : Wl2);
    const float* bl = g == 0 ? bl0 : (g == 1 ? bl1 : bl2);
    for (int q = 0; q < FF; q++) WcS[q][j] = Wc[q * HH + j];
    __syncthreads();
    float acc[FF];
#pragma unroll
    for (int i = 0; i < FF; i++) acc[i] = 0.0f;
    float accb = 0.0f;
    for (int k = 0; k < HH; k++) {
        float wl = Wl[k * HH + j];
        accb += bc[k] * wl;
#pragma unroll
        for (int i = 0; i < FF; i++) acc[i] += WcS[i][k] * wl;
    }
#pragma unroll
    for (int i = 0; i < FF; i++) Weff[(g * FF + i) * HH + j] = acc[i];
    beff[g * HH + j] = bl[j] + accb;
}

// C1: hp[n][:] = hm[n] ? h_state[n][:] : 0
__global__ void prep_hp(const float* __restrict__ hstate, const unsigned char* __restrict__ hm,
                        float* __restrict__ hp) {
    int gid = blockIdx.x * 256 + threadIdx.x;  // over NN*32 float4s
    int n = gid >> 5;
    float4 v = make_float4(0, 0, 0, 0);
    if (hm[n]) v = ((const float4*)hstate)[gid];
    ((float4*)hp)[gid] = v;
}

// G1: z/r gate GEMM. C[128x128] tile, K = 16 (xagg@Weff) + 128 (hp@Wl_bot).
__launch_bounds__(256)
__global__ void zr_gemm(const float* __restrict__ xagg, const float* __restrict__ hp,
                        const float* __restrict__ Weff, const float* __restrict__ beff,
                        const float* __restrict__ Wl0, const float* __restrict__ Wl1,
                        float* __restrict__ zbuf, float* __restrict__ rbuf) {
    __shared__ float As[16][MT + 2];
    __shared__ float Bs[16][132];
    const int tid = threadIdx.x;
    const int ty = tid >> 4;
    const int tx = tid & 15;
    const int m0 = blockIdx.x * MT;
    const int g = blockIdx.y;
    const float* Wl = g ? Wl1 : Wl0;
    const float* We = Weff + g * FF * HH;
    const float* be = beff + g * HH;
    float* ob = g ? rbuf : zbuf;

    float acc[8][8];
#pragma unroll
    for (int i = 0; i < 8; i++)
#pragma unroll
        for (int j = 0; j < 8; j++) acc[i][j] = 0.0f;

    const int arow = tid >> 1;
    const int ak0 = (tid & 1) * 8;
    const int bkk = tid >> 4;
    const int bc0 = (tid & 15) * 8;

    for (int ch = 0; ch < 9; ++ch) {
        float4 a0 = make_float4(0, 0, 0, 0), a1 = make_float4(0, 0, 0, 0);
        const int grow = m0 + arow;
        if (grow < NN) {
            const float* base = (ch == 0) ? (xagg + (size_t)grow * FF + ak0)
                                          : (hp + (size_t)grow * HH + (ch - 1) * 16 + ak0);
            a0 = *(const float4*)(base);
            a1 = *(const float4*)(base + 4);
        }
        const float* bsrc = (ch == 0) ? (We + bkk * HH + bc0)
                                      : (Wl + (size_t)(HH + (ch - 1) * 16 + bkk) * HH + bc0);
        float4 b0 = *(const float4*)(bsrc);
        float4 b1 = *(const float4*)(bsrc + 4);
        __syncthreads();
        As[ak0 + 0][arow] = a0.x; As[ak0 + 1][arow] = a0.y;
        As[ak0 + 2][arow] = a0.z; As[ak0 + 3][arow] = a0.w;
        As[ak0 + 4][arow] = a1.x; As[ak0 + 5][arow] = a1.y;
        As[ak0 + 6][arow] = a1.z; As[ak0 + 7][arow] = a1.w;
        *(float4*)&Bs[bkk][bc0] = b0;
        *(float4*)&Bs[bkk][bc0 + 4] = b1;
        __syncthreads();
#pragma unroll
        for (int kk = 0; kk < 16; kk++) {
            float a[8], b[8];
#pragma unroll
            for (int i = 0; i < 4; i++) {
                float2 t2 = *(const float2*)&As[kk][32 * i + 2 * ty];
                a[2 * i] = t2.x; a[2 * i + 1] = t2.y;
            }
#pragma unroll
            for (int j = 0; j < 4; j++) {
                float2 t2 = *(const float2*)&Bs[kk][32 * j + 2 * tx];
                b[2 * j] = t2.x; b[2 * j + 1] = t2.y;
            }
#pragma unroll
            for (int i = 0; i < 8; i++)
#pragma unroll
                for (int j = 0; j < 8; j++) acc[i][j] += a[i] * b[j];
        }
    }
#pragma unroll
    for (int i = 0; i < 4; i++)
#pragma unroll
        for (int ii = 0; ii < 2; ii++) {
            const int row = 32 * i + 2 * ty + ii;
            const int grow = m0 + row;
            if (grow < NN) {
#pragma unroll
                for (int j = 0; j < 4; j++) {
                    const int c0 = 32 * j + 2 * tx;
                    float2 bb = *(const float2*)&be[c0];
                    float2 v;
                    v.x = sigmoidf_(acc[2 * i + ii][2 * j + 0] + bb.x);
                    v.y = sigmoidf_(acc[2 * i + ii][2 * j + 1] + bb.y);
                    *(float2*)&ob[(size_t)grow * HH + c0] = v;
                }
            }
        }
}

// G2: h gate GEMM with fused h*r A-load and GRU/mask epilogue.
__launch_bounds__(256)
__global__ void h_gemm(const float* __restrict__ xagg, const float* __restrict__ hp,
                       const float* __restrict__ rbuf, const float* __restrict__ zbuf,
                       const float* __restrict__ Weff, const float* __restrict__ beff,
                       const float* __restrict__ Wl2, float* __restrict__ outb,
                       const unsigned char* __restrict__ mcmask) {
    __shared__ float As[16][MT + 2];
    __shared__ float Bs[16][132];
    const int tid = threadIdx.x;
    const int ty = tid >> 4;
    const int tx = tid & 15;
    const int m0 = blockIdx.x * MT;
    const float* We = Weff + 2 * FF * HH;
    const float* be = beff + 2 * HH;

    float acc[8][8];
#pragma unroll
    for (int i = 0; i < 8; i++)
#pragma unroll
        for (int j = 0; j < 8; j++) acc[i][j] = 0.0f;

    const int arow = tid >> 1;
    const int ak0 = (tid & 1) * 8;
    const int bkk = tid >> 4;
    const int bc0 = (tid & 15) * 8;

    for (int ch = 0; ch < 9; ++ch) {
        float4 a0 = make_float4(0, 0, 0, 0), a1 = make_float4(0, 0, 0, 0);
        const int grow = m0 + arow;
        if (grow < NN) {
            if (ch == 0) {
                const float* base = xagg + (size_t)grow * FF + ak0;
                a0 = *(const float4*)(base);
                a1 = *(const float4*)(base + 4);
            } else {
                const float* bh = hp + (size_t)grow * HH + (ch - 1) * 16 + ak0;
                const float* br = rbuf + (size_t)grow * HH + (ch - 1) * 16 + ak0;
                float4 h0 = *(const float4*)(bh), h1 = *(const float4*)(bh + 4);
                float4 r0 = *(const float4*)(br), r1 = *(const float4*)(br + 4);
                a0.x = h0.x * r0.x; a0.y = h0.y * r0.y; a0.z = h0.z * r0.z; a0.w = h0.w * r0.w;
                a1.x = h1.x * r1.x; a1.y = h1.y * r1.y; a1.z = h1.z * r1.z; a1.w = h1.w * r1.w;
            }
        }
        const float* bsrc = (ch == 0) ? (We + bkk * HH + bc0)
                                      : (Wl2 + (size_t)(HH + (ch - 1) * 16 + bkk) * HH + bc0);
        float4 b0 = *(const float4*)(bsrc);
        float4 b1 = *(const float4*)(bsrc + 4);
        __syncthreads();
        As[ak0 + 0][arow] = a0.x; As[ak0 + 1][arow] = a0.y;
        As[ak0 + 2][arow] = a0.z; As[ak0 + 3][arow] = a0.w;
        As[ak0 + 4][arow] = a1.x; As[ak0 + 5][arow] = a1.y;
        As[ak0 + 6][arow] = a1.z; As[ak0 + 7][arow] = a1.w;
        *(float4*)&Bs[bkk][bc0] = b0;
        *(float4*)&Bs[bkk][bc0 + 4] = b1;
        __syncthreads();
#pragma unroll
        for (int kk = 0; kk < 16; kk++) {
            float a[8], b[8];
#pragma unroll
            for (int i = 0; i < 4; i++) {
                float2 t2 = *(const float2*)&As[kk][32 * i + 2 * ty];
                a[2 * i] = t2.x; a[2 * i + 1] = t2.y;
            }
#pragma unroll
            for (int j = 0; j < 4; j++) {
                float2 t2 = *(const float2*)&Bs[kk][32 * j + 2 * tx];
                b[2 * j] = t2.x; b[2 * j + 1] = t2.y;
            }
#pragma unroll
            for (int i = 0; i < 8; i++)
#pragma unroll
                for (int j = 0; j < 8; j++) acc[i][j] += a[i] * b[j];
        }
    }
#pragma unroll
    for (int i = 0; i < 4; i++)
#pragma unroll
        for (int ii = 0; ii < 2; ii++) {
            const int row = 32 * i + 2 * ty + ii;
            const int grow = m0 + row;
            if (grow < NN) {
                bool m = (mcmask != nullptr) ? (mcmask[grow] != 0) : true;
#pragma unroll
                for (int j = 0; j < 4; j++) {
                    const int c0 = 32 * j + 2 * tx;
                    float2 bb = *(const float2*)&be[c0];
                    float2 z2 = *(const float2*)&zbuf[(size_t)grow * HH + c0];
                    float2 h2 = *(const float2*)&hp[(size_t)grow * HH + c0];
                    float ht0 = tanhf(acc[2 * i + ii][2 * j + 0] + bb.x);
                    float ht1 = tanhf(acc[2 * i + ii][2 * j + 1] + bb.y);
                    float2 v;
                    v.x = z2.x * h2.x + (1.0f - z2.x) * ht0;
                    v.y = z2.y * h2.y + (1.0f - z2.y) * ht1;
                    if (m) *(float2*)&outb[(size_t)grow * HH + c0] = v;
                }
            }
        }
}

// C4: out[n][o] = hp[n][:] . head_W[:,o] + head_b[o]; one wave per node
__global__ void head_kernel(const float* __restrict__ hp, const float* __restrict__ headW,
                            const float* __restrict__ headb, float* __restrict__ out) {
    int node = (blockIdx.x * 256 + threadIdx.x) >> 6;
    int lane = threadIdx.x & 63;
    if (node >= NN) return;
    const float* h = hp + (size_t)node * HH;
    float h0 = h[lane], h1 = h[64 + lane];
    float s0 = h0 * headW[lane * 3 + 0] + h1 * headW[(64 + lane) * 3 + 0];
    float s1 = h0 * headW[lane * 3 + 1] + h1 * headW[(64 + lane) * 3 + 1];
    float s2 = h0 * headW[lane * 3 + 2] + h1 * headW[(64 + lane) * 3 + 2];
#pragma unroll
    for (int off = 32; off > 0; off >>= 1) {
        s0 += __shfl_down(s0, off);
        s1 += __shfl_down(s1, off);
        s2 += __shfl_down(s2, off);
    }
    if (lane == 0) {
        out[(size_t)node * 3 + 0] = s0 + headb[0];
        out[(size_t)node * 3 + 1] = s1 + headb[1];
        out[(size_t)node * 3 + 2] = s2 + headb[2];
    }
}

extern "C" void kernel_launch(void* const* d_in, const int* in_sizes, int n_in,
                              void* d_out, int out_size, void* d_ws, size_t ws_size,
                              hipStream_t stream) {
    const float* x = (const float*)d_in[0];
    const int* ei = (const int*)d_in[1];
    const float* ea = (const float*)d_in[2];
    const void* mask = d_in[3];
    const float* Wc[3] = {(const float*)d_in[4], (const float*)d_in[8], (const float*)d_in[12]};
    const float* bc[3] = {(const float*)d_in[5], (const float*)d_in[9], (const float*)d_in[13]};
    const float* Wl[3] = {(const float*)d_in[6], (const float*)d_in[10], (const float*)d_in[14]};
    const float* bl[3] = {(const float*)d_in[7], (const float*)d_in[11], (const float*)d_in[15]};
    const float* headW = (const float*)d_in[16];
    const float* headb = (const float*)d_in[17];
    float* out = (float*)d_out;

    char* w = (char*)d_ws;
    auto alloc = [&](size_t bytes) {
        char* p = w;
        w += (bytes + 255) & ~(size_t)255;
        return p;
    };
    float* dinv = (float*)alloc((size_t)TT * NN * 4);
    float* xaggA = (float*)alloc((size_t)TT * NN * FF * 4);
    float* xaggH = (float*)alloc((size_t)NN * FF * 4);
    int* chunkHist = (int*)alloc((size_t)TT * BINS * NCH * 4);
    float* PW = (float*)alloc((size_t)24 * EE * 4);  // sorted packed + weights (12 slots each)
    float* Weff = (float*)alloc(3 * FF * HH * 4);
    float* beff = (float*)alloc(3 * HH * 4);
    unsigned char* hm = (unsigned char*)alloc((size_t)TT * NN);
    unsigned char* mc = (unsigned char*)alloc((size_t)TT * NN);
    int* flag = (int*)alloc(64);

    // Alias the recurrence buffers into dead sorted-edge slots (1..11);
    // slot 0 (= t 11) stays live for the horizon. NN*HH = 4*EE exactly.
    float* hstate = PW + (size_t)1 * EE;   // P slots 1..4
    float* hp     = PW + (size_t)5 * EE;   // P slots 5..8
    float* zbuf   = PW + (size_t)13 * EE;  // W slots 1..4
    float* rbuf   = PW + (size_t)17 * EE;  // W slots 5..8

    detect_mask<<<1, 256, 0, stream>>>((const unsigned char*)mask, flag);
    build_masks<<<(NN + 255) / 256, 256, 0, stream>>>(mask, flag, hm, mc);

    hist_kernel<<<dim3(NCH, TT), 256, 0, stream>>>(ei, chunkHist);
    scan_kernel<<<TT, 1024, 0, stream>>>(chunkHist);
    scatter_kernel<<<dim3(NCH, TT), 256, 0, stream>>>(ei, ea, chunkHist, PW);
    degsort_kernel<<<dim3(NBIN, TT), 256, 0, stream>>>(PW, chunkHist, dinv);
    gather_kernel<<<dim3(NBIN, TT), 512, 0, stream>>>(PW, chunkHist, dinv, x, xaggA);

    weight_kernel<<<3, 128, 0, stream>>>(Wc[0], bc[0], Wl[0], bl[0],
                                         Wc[1], bc[1], Wl[1], bl[1],
                                         Wc[2], bc[2], Wl[2], bl[2], Weff, beff);

    // hstate aliases sorted slots -> zero it only after the gathers are done
    hipMemsetAsync(hstate, 0, (size_t)NN * HH * 4, stream);

    // recurrent cells t = 0..11
    for (int t = 0; t < TT; t++) {
        prep_hp<<<NN * 32 / 256, 256, 0, stream>>>(hstate, hm + (size_t)t * NN, hp);
        zr_gemm<<<dim3(GB, 2), 256, 0, stream>>>(xaggA + (size_t)t * NN * FF, hp, Weff, beff,
                                                 Wl[0], Wl[1], zbuf, rbuf);
        h_gemm<<<GB, 256, 0, stream>>>(xaggA + (size_t)t * NN * FF, hp, rbuf, zbuf, Weff, beff,
                                       Wl[2], hstate, mc + (size_t)t * NN);
    }

    // horizon init: hp = mask[T-1] ? h_state : 0; xaggH = xagg(last graph, x_last)
    prep_hp<<<NN * 32 / 256, 256, 0, stream>>>(hstate, mc + (size_t)11 * NN, hp);
    hipMemcpyAsync(xaggH, xaggA + (size_t)11 * NN * FF, (size_t)NN * FF * 4,
                   hipMemcpyDeviceToDevice, stream);

    for (int k = 0; k < 6; k++) {
        const float* xa = (k == 0) ? (xaggA + (size_t)11 * NN * FF) : xaggH;
        zr_gemm<<<dim3(GB, 2), 256, 0, stream>>>(xa, hp, Weff, beff, Wl[0], Wl[1], zbuf, rbuf);
        h_gemm<<<GB, 256, 0, stream>>>(xa, hp, rbuf, zbuf, Weff, beff, Wl[2], hp, nullptr);
        head_kernel<<<NN * 64 / 256, 256, 0, stream>>>(hp, headW, headb, out + (size_t)k * NN * 3);
        if (k < 5) {
            gather3_kernel<<<NBIN, 256, 0, stream>>>(PW, chunkHist, dinv,
                                                     out + (size_t)k * NN * 3, xaggH);
        }
    }
}

// Round 3
// 3518.599 us; speedup vs baseline: 5.8888x; 1.4914x over previous
//
#include <hip/hip_runtime.h>
#include <math.h>

#define NN 50000
#define TT 12
#define EE 1600000
#define FF 16
#define HH 128
#define CHK 4096     // edges per chunk (level-1 histogram)
#define NCH 391      // ceil(EE/CHK)
#define BKT 128      // nodes per bin
#define NBINS 391    // ceil(NN/BKT) -> covers 50048
#define CAP 6144     // max edges per bin segment (mean 4096, sigma 64)
#define RP 50016     // rowptr stride per t (>= NN+1)
#define CGB 782      // ceil(NN/64) cell-gemm blocks
#define BSTRH 168    // LDS K-stride in halves (144 padded to 160, +8 anti-conflict)

typedef _Float16 half8_t __attribute__((ext_vector_type(8)));
typedef float floatx4 __attribute__((ext_vector_type(4)));

__device__ __forceinline__ float sigmoidf_(float x) { return 1.0f / (1.0f + expf(-x)); }

// ---------------------------------------------------------------------------
// P0: detect mask dtype from byte pattern (uint8 / int32 / float32).
__global__ void detect_mask(const unsigned char* __restrict__ m, int* __restrict__ flag) {
    __shared__ int cnt[2];
    if (threadIdx.x < 2) cnt[threadIdx.x] = 0;
    __syncthreads();
    int a = 0, b = 0;
    for (int base = 0; base < 4096; base += 256) {
        int idx = base + threadIdx.x;
        unsigned char v = m[idx];
        int r = idx & 3;
        if (v) { if (r == 0) a++; else if (r == 1) b++; }
    }
    atomicAdd(&cnt[0], a);
    atomicAdd(&cnt[1], b);
    __syncthreads();
    if (threadIdx.x == 0) flag[0] = cnt[1] > 0 ? 0 : (cnt[0] > 0 ? 1 : 2);
}

// P1: hm[t][n] = mask & seen-before, mc[t][n] = mask
__global__ void build_masks(const void* __restrict__ mask, const int* __restrict__ flag,
                            unsigned char* __restrict__ hm, unsigned char* __restrict__ mc) {
    int n = blockIdx.x * 256 + threadIdx.x;
    if (n >= NN) return;
    int mode = flag[0];
    bool seen = false;
    for (int t = 0; t < TT; t++) {
        int idx = t * NN + n;
        bool m;
        if (mode == 0)      m = ((const unsigned char*)mask)[idx] != 0;
        else if (mode == 1) m = ((const int*)mask)[idx] != 0;
        else                m = ((const float*)mask)[idx] != 0.0f;
        hm[idx] = (m && seen) ? 1 : 0;
        mc[idx] = m ? 1 : 0;
        seen = seen || m;
    }
}

// ---------------------------------------------------------------------------
// S1: per-chunk histogram of dst bins (bin = dst>>7). layout [t][bin][chunk]
__global__ void hist_kernel(const int* __restrict__ ei, int* __restrict__ chunkHist) {
    __shared__ int h[NBINS + 1];
    int c = blockIdx.x, t = blockIdx.y, tid = threadIdx.x;
    for (int i = tid; i < NBINS; i += 256) h[i] = 0;
    __syncthreads();
    const int* dstp = ei + (size_t)(2 * t + 1) * EE;
    int e0 = c * CHK;
    for (int i = tid; i < CHK; i += 256) {
        int e = e0 + i;
        if (e < EE) atomicAdd(&h[dstp[e] >> 7], 1);
    }
    __syncthreads();
    for (int i = tid; i < NBINS; i += 256)
        chunkHist[((size_t)t * NBINS + i) * NCH + c] = h[i];
}

// S2: in-place exclusive scan of each t's [NBINS*NCH] array
__global__ void scan_kernel(int* __restrict__ buf) {
    __shared__ int ps[1024];
    const int L = NBINS * NCH;   // 152881
    const int PER = 150;         // 1024*150 >= L
    int t = blockIdx.x, tid = threadIdx.x;
    int* a = buf + (size_t)t * L;
    int i0 = tid * PER, i1 = min(i0 + PER, L);
    int s = 0;
    for (int i = i0; i < i1; i++) s += a[i];
    ps[tid] = s;
    __syncthreads();
    for (int off = 1; off < 1024; off <<= 1) {
        int v = (tid >= off) ? ps[tid - off] : 0;
        __syncthreads();
        ps[tid] += v;
        __syncthreads();
    }
    int base = (tid == 0) ? 0 : ps[tid - 1];
    for (int i = i0; i < i1; i++) { int v = a[i]; a[i] = base; base += v; }
}

// S3: scatter edges into bin-sorted order. Packed: src | (dloc<<17).
// Slot remap: slot(t)=(t+1)%12 so t=11 lands in slot 0 (survives aliasing).
__global__ void scatter_kernel(const int* __restrict__ ei, const float* __restrict__ ea,
                               const int* __restrict__ chunkOff, float* __restrict__ PW) {
    __shared__ int cur[NBINS + 1];
    int c = blockIdx.x, t = blockIdx.y, tid = threadIdx.x;
    for (int i = tid; i < NBINS; i += 256)
        cur[i] = chunkOff[((size_t)t * NBINS + i) * NCH + c];
    __syncthreads();
    int sl = (t + 1) % 12;
    unsigned int* sp = (unsigned int*)PW + (size_t)sl * EE;
    float* sw = PW + (size_t)(12 + sl) * EE;
    const int* srcp = ei + (size_t)(2 * t) * EE;
    const int* dstp = ei + (size_t)(2 * t + 1) * EE;
    const float* wp = ea + (size_t)t * EE;
    int e0 = c * CHK;
    for (int i = tid; i < CHK; i += 256) {
        int e = e0 + i;
        if (e < EE) {
            int d = dstp[e];
            int b = d >> 7;
            int pos = atomicAdd(&cur[b], 1);
            sp[pos] = (unsigned int)srcp[e] | ((unsigned int)(d & 127) << 17);
            sw[pos] = wp[e];
        }
    }
}

// S4: in-place per-bin counting sort -> node-sorted CSR + rowptr + dinv.
__launch_bounds__(256)
__global__ void sortbin_kernel(float* __restrict__ PW, const int* __restrict__ chunkHist,
                               int* __restrict__ rowptr, float* __restrict__ dinvG) {
    __shared__ unsigned int esp[CAP];
    __shared__ float esw[CAP];
    __shared__ int cnt[BKT];
    __shared__ float wsm[BKT];
    __shared__ int cur[BKT];
    int b = blockIdx.x, t = blockIdx.y, tid = threadIdx.x;
    int sl = (t + 1) % 12;
    unsigned int* gsp = (unsigned int*)PW + (size_t)sl * EE;
    float* gsw = PW + (size_t)(12 + sl) * EE;
    const int* off = chunkHist + (size_t)t * NBINS * NCH;
    int e0 = off[b * NCH];
    int e1 = (b == NBINS - 1) ? EE : off[(b + 1) * NCH];
    int seg = e1 - e0;
    for (int i = tid; i < seg; i += 256) { esp[i] = gsp[e0 + i]; esw[i] = gsw[e0 + i]; }
    if (tid < BKT) { cnt[tid] = 0; wsm[tid] = 0.0f; }
    __syncthreads();
    for (int i = tid; i < seg; i += 256) {
        int dl = esp[i] >> 17;
        atomicAdd(&cnt[dl], 1);
        atomicAdd(&wsm[dl], esw[i]);
    }
    __syncthreads();
    int ogv = (tid < BKT) ? cnt[tid] : 0;
    for (int o = 1; o < BKT; o <<= 1) {
        int u = (tid < BKT && tid >= o) ? cnt[tid - o] : 0;
        __syncthreads();
        if (tid < BKT) cnt[tid] += u;
        __syncthreads();
    }
    if (tid < BKT) {
        int exc = cnt[tid] - ogv;
        cur[tid] = exc;
        int node = b * BKT + tid;
        if (node <= NN) {
            rowptr[(size_t)t * RP + node] = e0 + exc;
            if (node < NN) dinvG[(size_t)t * NN + node] = rsqrtf(1.0f + wsm[tid]);
        }
    }
    __syncthreads();
    for (int i = tid; i < seg; i += 256) {
        unsigned int p = esp[i];
        int dl = p >> 17;
        int pos = atomicAdd(&cur[dl], 1);
        gsp[e0 + pos] = p & 0x1FFFF;
        gsw[e0 + pos] = esw[i];
    }
}

// S5: CSR gather: wave per (t, node). lane = (edge%4)*16 + feature.
__global__ void gather_csr(const float* __restrict__ PW, const int* __restrict__ rowptr,
                           const float* __restrict__ dinvG, const float* __restrict__ x,
                           float* __restrict__ xagg) {
    int t = blockIdx.y;
    int n = blockIdx.x * 4 + (threadIdx.x >> 6);
    if (n >= NN) return;
    int lane = threadIdx.x & 63;
    int eo = lane >> 4, f = lane & 15;
    int sl = (t + 1) % 12;
    const unsigned int* gsp = (const unsigned int*)PW + (size_t)sl * EE;
    const float* gsw = PW + (size_t)(12 + sl) * EE;
    const float* dv = dinvG + (size_t)t * NN;
    const float* xt = x + (size_t)t * NN * FF;
    int r0 = rowptr[(size_t)t * RP + n], r1 = rowptr[(size_t)t * RP + n + 1];
    float acc = 0.0f;
    for (int e = r0 + eo; e < r1; e += 4) {
        int s = gsp[e];
        float nm = gsw[e] * dv[s];
        acc += nm * xt[(size_t)s * FF + f];
    }
    acc += __shfl_xor(acc, 16);
    acc += __shfl_xor(acc, 32);
    float dd = dv[n];
    float res = dd * acc + dd * dd * xt[(size_t)n * FF + f];
    if (lane < 16) xagg[((size_t)t * NN + n) * FF + f] = res;
}

// S6 (horizon): 3-feature CSR re-aggregation of pred over the t=11 graph.
__global__ void gather3_csr(const float* __restrict__ PW, const int* __restrict__ rowptr,
                            const float* __restrict__ dinvG, const float* __restrict__ pred,
                            float* __restrict__ xaggH) {
    int n = blockIdx.x * 4 + (threadIdx.x >> 6);
    if (n >= NN) return;
    int lane = threadIdx.x & 63;
    int eo = lane >> 2, f = lane & 3;
    const unsigned int* gsp = (const unsigned int*)PW;            // slot 0 = t 11
    const float* gsw = PW + (size_t)12 * EE;
    const float* dv = dinvG + (size_t)11 * NN;
    int r0 = rowptr[(size_t)11 * RP + n], r1 = rowptr[(size_t)11 * RP + n + 1];
    float acc = 0.0f;
    for (int e = r0 + eo; e < r1; e += 16) {
        int s = gsp[e];
        float nm = gsw[e] * dv[s];
        if (f < 3) acc += nm * pred[(size_t)s * 3 + f];
    }
    acc += __shfl_xor(acc, 4);
    acc += __shfl_xor(acc, 8);
    acc += __shfl_xor(acc, 16);
    acc += __shfl_xor(acc, 32);
    if (lane < 3) {
        float dd = dv[n];
        xaggH[(size_t)n * FF + f] = dd * acc + dd * dd * pred[(size_t)n * 3 + f];
    }
}

// ---------------------------------------------------------------------------
// W: fold Wc into Wl_top -> Bcat[g][144][128] (f16), beff[g][128] (f32)
__global__ void weight_kernel(const float* Wc0, const float* bc0, const float* Wl0, const float* bl0,
                              const float* Wc1, const float* bc1, const float* Wl1, const float* bl1,
                              const float* Wc2, const float* bc2, const float* Wl2, const float* bl2,
                              _Float16* __restrict__ Bcat, float* __restrict__ beff) {
    __shared__ float WcS[FF][HH];
    int g = blockIdx.x;
    int n = threadIdx.x;  // 128
    const float* Wc = g == 0 ? Wc0 : (g == 1 ? Wc1 : Wc2);
    const float* bc = g == 0 ? bc0 : (g == 1 ? bc1 : bc2);
    const float* Wl = g == 0 ? Wl0 : (g == 1 ? Wl1 : Wl2);
    const float* bl = g == 0 ? bl0 : (g == 1 ? bl1 : bl2);
    for (int q = 0; q < FF; q++) WcS[q][n] = Wc[q * HH + n];
    __syncthreads();
    float acc[FF];
#pragma unroll
    for (int i = 0; i < FF; i++) acc[i] = 0.0f;
    float accb = 0.0f;
    for (int k = 0; k < HH; k++) {
        float wl = Wl[k * HH + n];
        accb += bc[k] * wl;
#pragma unroll
        for (int i = 0; i < FF; i++) acc[i] += WcS[i][k] * wl;
    }
#pragma unroll
    for (int i = 0; i < FF; i++) Bcat[((size_t)g * 144 + i) * HH + n] = (_Float16)acc[i];
    for (int j = 0; j < HH; j++)
        Bcat[((size_t)g * 144 + 16 + j) * HH + n] = (_Float16)Wl[(size_t)(HH + j) * HH + n];
    beff[g * HH + n] = bl[n] + accb;
}

// C1: hp[n][:] = m[n] ? h_state[n][:] : 0
__global__ void prep_hp(const float* __restrict__ hstate, const unsigned char* __restrict__ m,
                        float* __restrict__ hp) {
    int gid = blockIdx.x * 256 + threadIdx.x;  // NN*32 float4s
    int n = gid >> 5;
    float4 v = make_float4(0, 0, 0, 0);
    if (m[n]) v = ((const float4*)hstate)[gid];
    ((float4*)hp)[gid] = v;
}

// ---------------------------------------------------------------------------
// CELL: fused z/r/h~ f16-MFMA GRU cell. 64 rows/block, 4 waves, K=144 (pad 160).
// hmask: null -> h_prev = hstate; else gate by hmask. mcmask: null -> always
// store; else conditional (in-place hstate update).
__launch_bounds__(256)
__global__ void cell_kernel(const float* __restrict__ xagg, const float* __restrict__ hstate,
                            const _Float16* __restrict__ Bcat, const float* __restrict__ beff,
                            const unsigned char* __restrict__ hmask,
                            const unsigned char* __restrict__ mcmask,
                            float* __restrict__ outh) {
    __shared__ _Float16 As[64 * BSTRH];    // 21504 B
    __shared__ _Float16 Bs[128 * BSTRH];   // 43008 B (one gate at a time; also rT scratch)
    const int tid = threadIdx.x;
    const int m0 = blockIdx.x * 64;
    const int lane = tid & 63;
    const int w = tid >> 6;
    const int mrow = lane & 15;
    const int quad = lane >> 4;

    // --- stage A: [xagg(16) | h_prev(128)] as f16, pad k=144..159 ---
    {
        int row = tid >> 2, q = tid & 3;
        int g = m0 + row;
        float4 v = make_float4(0, 0, 0, 0);
        if (g < NN) v = *(const float4*)(xagg + (size_t)g * FF + 4 * q);
        _Float16* p = As + row * BSTRH + 4 * q;
        p[0] = (_Float16)v.x; p[1] = (_Float16)v.y; p[2] = (_Float16)v.z; p[3] = (_Float16)v.w;
        _Float16* pp = As + row * BSTRH + 144 + 4 * q;
        pp[0] = (_Float16)0; pp[1] = (_Float16)0; pp[2] = (_Float16)0; pp[3] = (_Float16)0;
    }
    for (int idx = tid; idx < 64 * 32; idx += 256) {
        int row = idx >> 5, q = idx & 31;
        int g = m0 + row;
        float4 v = make_float4(0, 0, 0, 0);
        if (g < NN && (hmask == nullptr || hmask[g]))
            v = *(const float4*)(hstate + (size_t)g * HH + 4 * q);
        _Float16* p = As + row * BSTRH + 16 + 4 * q;
        p[0] = (_Float16)v.x; p[1] = (_Float16)v.y; p[2] = (_Float16)v.z; p[3] = (_Float16)v.w;
    }

    // A fragments (rows w*16..w*16+15), reused for z and r gemms
    const _Float16* Abase = As + (w * 16 + mrow) * BSTRH + quad * 8;
    const _Float16* Bbase = Bs + mrow * BSTRH + quad * 8;

    floatx4 zacc[8], racc[8];
#pragma unroll
    for (int c = 0; c < 8; c++)
#pragma unroll
        for (int i = 0; i < 4; i++) { zacc[c][i] = 0.0f; racc[c][i] = 0.0f; }

    // ---- gate z ----
    for (int idx = tid; idx < 144 * 128; idx += 256) {
        int k = idx >> 7, n = idx & 127;
        Bs[n * BSTRH + k] = Bcat[idx];
    }
    for (int idx = tid; idx < 128 * 16; idx += 256)
        Bs[(idx >> 4) * BSTRH + 144 + (idx & 15)] = (_Float16)0;
    __syncthreads();
    half8_t a_frag[5];
#pragma unroll
    for (int ks = 0; ks < 5; ks++) a_frag[ks] = *(const half8_t*)(Abase + ks * 32);
#pragma unroll
    for (int ks = 0; ks < 5; ks++)
#pragma unroll
        for (int c = 0; c < 8; c++) {
            half8_t b = *(const half8_t*)(Bbase + c * 16 * BSTRH + ks * 32);
            zacc[c] = __builtin_amdgcn_mfma_f32_16x16x32_f16(a_frag[ks], b, zacc[c], 0, 0, 0);
        }
    __syncthreads();
    // ---- gate r ----
    for (int idx = tid; idx < 144 * 128; idx += 256) {
        int k = idx >> 7, n = idx & 127;
        Bs[n * BSTRH + k] = Bcat[144 * 128 + idx];
    }
    __syncthreads();
#pragma unroll
    for (int ks = 0; ks < 5; ks++)
#pragma unroll
        for (int c = 0; c < 8; c++) {
            half8_t b = *(const half8_t*)(Bbase + c * 16 * BSTRH + ks * 32);
            racc[c] = __builtin_amdgcn_mfma_f32_16x16x32_f16(a_frag[ks], b, racc[c], 0, 0, 0);
        }
    __syncthreads();
    // ---- r -> LDS (reuse Bs), then As.h *= r ----
    _Float16* rT = Bs;  // 64 x 130
#pragma unroll
    for (int c = 0; c < 8; c++)
#pragma unroll
        for (int i = 0; i < 4; i++) {
            int row = w * 16 + quad * 4 + i;
            int col = c * 16 + mrow;
            rT[row * 130 + col] = (_Float16)sigmoidf_(racc[c][i] + beff[HH + col]);
        }
    __syncthreads();
    for (int idx = tid; idx < 64 * 128; idx += 256) {
        int row = idx >> 7, col = idx & 127;
        As[row * BSTRH + 16 + col] = As[row * BSTRH + 16 + col] * rT[row * 130 + col];
    }
    __syncthreads();
    // ---- gate h~ ----
    for (int idx = tid; idx < 144 * 128; idx += 256) {
        int k = idx >> 7, n = idx & 127;
        Bs[n * BSTRH + k] = Bcat[2 * 144 * 128 + idx];
    }
    for (int idx = tid; idx < 128 * 16; idx += 256)
        Bs[(idx >> 4) * BSTRH + 144 + (idx & 15)] = (_Float16)0;  // re-zero (rT clobbered pads)
    __syncthreads();
    floatx4 hacc[8];
#pragma unroll
    for (int c = 0; c < 8; c++)
#pragma unroll
        for (int i = 0; i < 4; i++) hacc[c][i] = 0.0f;
#pragma unroll
    for (int ks = 0; ks < 5; ks++) {
        half8_t a = *(const half8_t*)(Abase + ks * 32);
#pragma unroll
        for (int c = 0; c < 8; c++) {
            half8_t b = *(const half8_t*)(Bbase + c * 16 * BSTRH + ks * 32);
            hacc[c] = __builtin_amdgcn_mfma_f32_16x16x32_f16(a, b, hacc[c], 0, 0, 0);
        }
    }
    // ---- epilogue: h_new = z*h_prev + (1-z)*tanh(h~), masked store ----
#pragma unroll
    for (int c = 0; c < 8; c++) {
        int col = c * 16 + mrow;
        float bz = beff[col];
        float bh = beff[2 * HH + col];
#pragma unroll
        for (int i = 0; i < 4; i++) {
            int g = m0 + w * 16 + quad * 4 + i;
            if (g < NN) {
                float z = sigmoidf_(zacc[c][i] + bz);
                float ht = tanhf(hacc[c][i] + bh);
                float hs = hstate[(size_t)g * HH + col];
                float hpv = (hmask == nullptr || hmask[g]) ? hs : 0.0f;
                float hn = z * hpv + (1.0f - z) * ht;
                if (mcmask == nullptr || mcmask[g])
                    outh[(size_t)g * HH + col] = hn;
            }
        }
    }
}

// C4: out[n][o] = h[n][:] . head_W[:,o] + head_b[o]; one wave per node
__global__ void head_kernel(const float* __restrict__ hp, const float* __restrict__ headW,
                            const float* __restrict__ headb, float* __restrict__ out) {
    int node = (blockIdx.x * 256 + threadIdx.x) >> 6;
    int lane = threadIdx.x & 63;
    if (node >= NN) return;
    const float* h = hp + (size_t)node * HH;
    float h0 = h[lane], h1 = h[64 + lane];
    float s0 = h0 * headW[lane * 3 + 0] + h1 * headW[(64 + lane) * 3 + 0];
    float s1 = h0 * headW[lane * 3 + 1] + h1 * headW[(64 + lane) * 3 + 1];
    float s2 = h0 * headW[lane * 3 + 2] + h1 * headW[(64 + lane) * 3 + 2];
#pragma unroll
    for (int off = 32; off > 0; off >>= 1) {
        s0 += __shfl_down(s0, off);
        s1 += __shfl_down(s1, off);
        s2 += __shfl_down(s2, off);
    }
    if (lane == 0) {
        out[(size_t)node * 3 + 0] = s0 + headb[0];
        out[(size_t)node * 3 + 1] = s1 + headb[1];
        out[(size_t)node * 3 + 2] = s2 + headb[2];
    }
}

extern "C" void kernel_launch(void* const* d_in, const int* in_sizes, int n_in,
                              void* d_out, int out_size, void* d_ws, size_t ws_size,
                              hipStream_t stream) {
    const float* x = (const float*)d_in[0];
    const int* ei = (const int*)d_in[1];
    const float* ea = (const float*)d_in[2];
    const void* mask = d_in[3];
    const float* Wc[3] = {(const float*)d_in[4], (const float*)d_in[8], (const float*)d_in[12]};
    const float* bc[3] = {(const float*)d_in[5], (const float*)d_in[9], (const float*)d_in[13]};
    const float* Wl[3] = {(const float*)d_in[6], (const float*)d_in[10], (const float*)d_in[14]};
    const float* bl[3] = {(const float*)d_in[7], (const float*)d_in[11], (const float*)d_in[15]};
    const float* headW = (const float*)d_in[16];
    const float* headb = (const float*)d_in[17];
    float* out = (float*)d_out;

    char* w = (char*)d_ws;
    auto alloc = [&](size_t bytes) {
        char* p = w;
        w += (bytes + 255) & ~(size_t)255;
        return p;
    };
    float* dinv = (float*)alloc((size_t)TT * NN * 4);
    float* xaggA = (float*)alloc((size_t)TT * NN * FF * 4);
    float* xaggH = (float*)alloc((size_t)NN * FF * 4);
    int* chunkHist = (int*)alloc((size_t)TT * NBINS * NCH * 4);
    int* rowptr = (int*)alloc((size_t)TT * RP * 4);
    float* PW = (float*)alloc((size_t)24 * EE * 4);  // sp slots 0..11 (int), sw slots 12..23
    _Float16* Bcat = (_Float16*)alloc((size_t)3 * 144 * HH * 2);
    float* beff = (float*)alloc(3 * HH * 4);
    unsigned char* hm = (unsigned char*)alloc((size_t)TT * NN);
    unsigned char* mc = (unsigned char*)alloc((size_t)TT * NN);
    int* flag = (int*)alloc(64);

    // Aliases in PW: sp slots 1..11 are dead after gather_csr (slot 0 = t 11
    // survives for the horizon). NN*HH = 4*EE exactly.
    float* hstate = PW + (size_t)1 * EE;  // sp slots 1..4
    float* hph    = PW + (size_t)5 * EE;  // sp slots 5..8

    detect_mask<<<1, 256, 0, stream>>>((const unsigned char*)mask, flag);
    build_masks<<<(NN + 255) / 256, 256, 0, stream>>>(mask, flag, hm, mc);

    hist_kernel<<<dim3(NCH, TT), 256, 0, stream>>>(ei, chunkHist);
    scan_kernel<<<TT, 1024, 0, stream>>>(chunkHist);
    scatter_kernel<<<dim3(NCH, TT), 256, 0, stream>>>(ei, ea, chunkHist, PW);
    sortbin_kernel<<<dim3(NBINS, TT), 256, 0, stream>>>(PW, chunkHist, rowptr, dinv);
    gather_csr<<<dim3((NN + 3) / 4, TT), 256, 0, stream>>>(PW, rowptr, dinv, x, xaggA);

    weight_kernel<<<3, 128, 0, stream>>>(Wc[0], bc[0], Wl[0], bl[0],
                                         Wc[1], bc[1], Wl[1], bl[1],
                                         Wc[2], bc[2], Wl[2], bl[2], Bcat, beff);

    // hstate aliases sp slots -> zero only after gathers consumed them
    hipMemsetAsync(hstate, 0, (size_t)NN * HH * 4, stream);

    // recurrent cells t = 0..11 (in-place hstate update, mask-gated)
    for (int t = 0; t < TT; t++) {
        cell_kernel<<<CGB, 256, 0, stream>>>(xaggA + (size_t)t * NN * FF, hstate, Bcat, beff,
                                             hm + (size_t)t * NN, mc + (size_t)t * NN, hstate);
    }

    // horizon: hph = mask[T-1] ? h_state : 0, then unconditional GRU chain
    prep_hp<<<NN * 32 / 256, 256, 0, stream>>>(hstate, mc + (size_t)11 * NN, hph);
    hipMemcpyAsync(xaggH, xaggA + (size_t)11 * NN * FF, (size_t)NN * FF * 4,
                   hipMemcpyDeviceToDevice, stream);

    for (int k = 0; k < 6; k++) {
        const float* xa = (k == 0) ? (xaggA + (size_t)11 * NN * FF) : xaggH;
        cell_kernel<<<CGB, 256, 0, stream>>>(xa, hph, Bcat, beff, nullptr, nullptr, hph);
        head_kernel<<<NN * 64 / 256, 256, 0, stream>>>(hph, headW, headb, out + (size_t)k * NN * 3);
        if (k < 5) {
            gather3_csr<<<(NN + 3) / 4, 256, 0, stream>>>(PW, rowptr, dinv,
                                                          out + (size_t)k * NN * 3, xaggH);
        }
    }
}

// Round 4
// 2783.097 us; speedup vs baseline: 7.4451x; 1.2643x over previous
//
#include <hip/hip_runtime.h>
#include <math.h>

#define NN 50000
#define TT 12
#define EE 1600000
#define FF 16
#define HH 128
#define CHK 4096     // edges per chunk (level-1 histogram / scatter staging)
#define NCH 391      // ceil(EE/CHK)
#define BKT 128      // nodes per bin
#define NBINS 391    // ceil(NN/BKT) -> covers 50048
#define CAP 6144     // max edges per bin segment (mean 4096, sigma 64)
#define RP 50016     // rowptr stride per t (>= NN+1)
#define CGB 782      // ceil(NN/64) cell blocks
#define BSTRH 168    // LDS K-stride in halves (144 padded to 160, +8 anti-conflict)

typedef _Float16 half8_t __attribute__((ext_vector_type(8)));
typedef float floatx4 __attribute__((ext_vector_type(4)));

__device__ __forceinline__ float sigmoidf_(float x) { return 1.0f / (1.0f + expf(-x)); }

// ---------------------------------------------------------------------------
// P0: detect mask dtype from byte pattern (uint8 / int32 / float32).
__global__ void detect_mask(const unsigned char* __restrict__ m, int* __restrict__ flag) {
    __shared__ int cnt[2];
    if (threadIdx.x < 2) cnt[threadIdx.x] = 0;
    __syncthreads();
    int a = 0, b = 0;
    for (int base = 0; base < 4096; base += 256) {
        int idx = base + threadIdx.x;
        unsigned char v = m[idx];
        int r = idx & 3;
        if (v) { if (r == 0) a++; else if (r == 1) b++; }
    }
    atomicAdd(&cnt[0], a);
    atomicAdd(&cnt[1], b);
    __syncthreads();
    if (threadIdx.x == 0) flag[0] = cnt[1] > 0 ? 0 : (cnt[0] > 0 ? 1 : 2);
}

// P1: hm[t][n] = mask & seen-before, mc[t][n] = mask
__global__ void build_masks(const void* __restrict__ mask, const int* __restrict__ flag,
                            unsigned char* __restrict__ hm, unsigned char* __restrict__ mc) {
    int n = blockIdx.x * 256 + threadIdx.x;
    if (n >= NN) return;
    int mode = flag[0];
    bool seen = false;
    for (int t = 0; t < TT; t++) {
        int idx = t * NN + n;
        bool m;
        if (mode == 0)      m = ((const unsigned char*)mask)[idx] != 0;
        else if (mode == 1) m = ((const int*)mask)[idx] != 0;
        else                m = ((const float*)mask)[idx] != 0.0f;
        hm[idx] = (m && seen) ? 1 : 0;
        mc[idx] = m ? 1 : 0;
        seen = seen || m;
    }
}

// ---------------------------------------------------------------------------
// S1: per-chunk histogram of dst bins (bin = dst>>7). layout [t][bin][chunk]
__global__ void hist_kernel(const int* __restrict__ ei, int* __restrict__ chunkHist) {
    __shared__ int h[NBINS + 1];
    int c = blockIdx.x, t = blockIdx.y, tid = threadIdx.x;
    for (int i = tid; i < NBINS; i += 256) h[i] = 0;
    __syncthreads();
    const int* dstp = ei + (size_t)(2 * t + 1) * EE;
    int e0 = c * CHK;
    for (int i = tid; i < CHK; i += 256) {
        int e = e0 + i;
        if (e < EE) atomicAdd(&h[dstp[e] >> 7], 1);
    }
    __syncthreads();
    for (int i = tid; i < NBINS; i += 256)
        chunkHist[((size_t)t * NBINS + i) * NCH + c] = h[i];
}

// S2: in-place exclusive scan of each t's [NBINS*NCH] array
__global__ void scan_kernel(int* __restrict__ buf) {
    __shared__ int ps[1024];
    const int L = NBINS * NCH;   // 152881
    const int PER = 150;         // 1024*150 >= L
    int t = blockIdx.x, tid = threadIdx.x;
    int* a = buf + (size_t)t * L;
    int i0 = tid * PER, i1 = min(i0 + PER, L);
    int s = 0;
    for (int i = i0; i < i1; i++) s += a[i];
    ps[tid] = s;
    __syncthreads();
    for (int off = 1; off < 1024; off <<= 1) {
        int v = (tid >= off) ? ps[tid - off] : 0;
        __syncthreads();
        ps[tid] += v;
        __syncthreads();
    }
    int base = (tid == 0) ? 0 : ps[tid - 1];
    for (int i = i0; i < i1; i++) { int v = a[i]; a[i] = base; base += v; }
}

// S3: LDS-staged scatter into bin-sorted order. Record: uint2{src|dst<<16, w}.
// Per chunk: reg-cache edges, LDS rank+scan, place into LDS in bin order,
// then COALESCED segment write-out (consecutive i -> consecutive gpos).
// Slot remap: slot(t)=(t+1)%12 so t=11 lands in slot 0 (survives aliasing).
__launch_bounds__(256)
__global__ void scatter_kernel(const int* __restrict__ ei, const float* __restrict__ ea,
                               const int* __restrict__ chunkOff, uint2* __restrict__ E2) {
    __shared__ uint2 sorted[CHK];          // 32 KB
    __shared__ int cnt[NBINS];
    __shared__ int sA[NBINS], sB[NBINS];
    __shared__ int start[NBINS], gbase[NBINS];
    int c = blockIdx.x, t = blockIdx.y, tid = threadIdx.x;
    for (int i = tid; i < NBINS; i += 256) {
        cnt[i] = 0;
        gbase[i] = chunkOff[((size_t)t * NBINS + i) * NCH + c];
    }
    __syncthreads();
    const int* srcp = ei + (size_t)(2 * t) * EE;
    const int* dstp = ei + (size_t)(2 * t + 1) * EE;
    const float* wp = ea + (size_t)t * EE;
    int e0 = c * CHK;
    int m = min(CHK, EE - e0);
    uint2 rec[16];
    int rank[16];
#pragma unroll
    for (int k = 0; k < 16; k++) {
        int i = k * 256 + tid;
        rank[k] = -1;
        if (i < m) {
            int e = e0 + i;
            unsigned int s = (unsigned int)srcp[e];
            unsigned int d = (unsigned int)dstp[e];
            float wv = wp[e];
            rec[k].x = s | (d << 16);
            rec[k].y = __float_as_uint(wv);
            rank[k] = atomicAdd(&cnt[d >> 7], 1);
        }
    }
    __syncthreads();
    // exclusive scan over cnt (Hillis-Steele ping-pong)
    for (int i = tid; i < NBINS; i += 256) sA[i] = cnt[i];
    __syncthreads();
    int pp = 0;
    for (int off = 1; off < NBINS; off <<= 1) {
        if (pp == 0) {
            for (int i = tid; i < NBINS; i += 256)
                sB[i] = (i >= off) ? sA[i] + sA[i - off] : sA[i];
        } else {
            for (int i = tid; i < NBINS; i += 256)
                sA[i] = (i >= off) ? sB[i] + sB[i - off] : sB[i];
        }
        pp ^= 1;
        __syncthreads();
    }
    const int* inc = pp ? sB : sA;
    for (int i = tid; i < NBINS; i += 256) start[i] = inc[i] - cnt[i];
    __syncthreads();
    // place into LDS in bin-sorted order
#pragma unroll
    for (int k = 0; k < 16; k++) {
        if (rank[k] >= 0) {
            int b = rec[k].x >> 23;
            sorted[start[b] + rank[k]] = rec[k];
        }
    }
    __syncthreads();
    // coalesced write-out
    int sl = (t + 1) % 12;
    uint2* outp = E2 + (size_t)sl * EE;
    for (int i = tid; i < m; i += 256) {
        uint2 r = sorted[i];
        int b = r.x >> 23;
        outp[gbase[b] + (i - start[b])] = r;
    }
}

// S4: in-place per-bin counting sort -> node-sorted CSR + rowptr + dinv.
__launch_bounds__(256)
__global__ void sortbin_kernel(uint2* __restrict__ E2, const int* __restrict__ chunkHist,
                               int* __restrict__ rowptr, float* __restrict__ dinvG) {
    __shared__ uint2 es[CAP];   // 48 KB
    __shared__ int cnt[BKT];
    __shared__ float wsm[BKT];
    __shared__ int cur[BKT];
    int b = blockIdx.x, t = blockIdx.y, tid = threadIdx.x;
    int sl = (t + 1) % 12;
    uint2* gE = E2 + (size_t)sl * EE;
    const int* off = chunkHist + (size_t)t * NBINS * NCH;
    int e0 = off[b * NCH];
    int e1 = (b == NBINS - 1) ? EE : off[(b + 1) * NCH];
    int seg = e1 - e0;
    for (int i = tid; i < seg; i += 256) es[i] = gE[e0 + i];
    if (tid < BKT) { cnt[tid] = 0; wsm[tid] = 0.0f; }
    __syncthreads();
    for (int i = tid; i < seg; i += 256) {
        int dl = (es[i].x >> 16) & 127;
        atomicAdd(&cnt[dl], 1);
        atomicAdd(&wsm[dl], __uint_as_float(es[i].y));
    }
    __syncthreads();
    int ogv = (tid < BKT) ? cnt[tid] : 0;
    for (int o = 1; o < BKT; o <<= 1) {
        int u = (tid < BKT && tid >= o) ? cnt[tid - o] : 0;
        __syncthreads();
        if (tid < BKT) cnt[tid] += u;
        __syncthreads();
    }
    if (tid < BKT) {
        int exc = cnt[tid] - ogv;
        cur[tid] = exc;
        int node = b * BKT + tid;
        if (node <= NN) {
            rowptr[(size_t)t * RP + node] = e0 + exc;
            if (node < NN) dinvG[(size_t)t * NN + node] = rsqrtf(1.0f + wsm[tid]);
        }
    }
    __syncthreads();
    for (int i = tid; i < seg; i += 256) {
        uint2 p = es[i];
        int dl = (p.x >> 16) & 127;
        int pos = atomicAdd(&cur[dl], 1);
        gE[e0 + pos] = make_uint2(p.x & 0xFFFF, p.y);   // keep src only + w
    }
}

// S5: CSR gather: wave per (t, node). lane = (edge%4)*16 + feature.
__global__ void gather_csr(const uint2* __restrict__ E2, const int* __restrict__ rowptr,
                           const float* __restrict__ dinvG, const float* __restrict__ x,
                           float* __restrict__ xagg) {
    int t = blockIdx.y;
    int n = blockIdx.x * 4 + (threadIdx.x >> 6);
    if (n >= NN) return;
    int lane = threadIdx.x & 63;
    int eo = lane >> 4, f = lane & 15;
    int sl = (t + 1) % 12;
    const uint2* gE = E2 + (size_t)sl * EE;
    const float* dv = dinvG + (size_t)t * NN;
    const float* xt = x + (size_t)t * NN * FF;
    int r0 = rowptr[(size_t)t * RP + n], r1 = rowptr[(size_t)t * RP + n + 1];
    float acc = 0.0f;
    for (int e = r0 + eo; e < r1; e += 4) {
        uint2 rc = gE[e];
        int s = rc.x;
        float nm = __uint_as_float(rc.y) * dv[s];
        acc += nm * xt[(size_t)s * FF + f];
    }
    acc += __shfl_xor(acc, 16);
    acc += __shfl_xor(acc, 32);
    float dd = dv[n];
    float res = dd * acc + dd * dd * xt[(size_t)n * FF + f];
    if (lane < 16) xagg[((size_t)t * NN + n) * FF + f] = res;
}

// S6 (horizon): 3-feature CSR re-aggregation of pred over the t=11 graph.
__global__ void gather3_csr(const uint2* __restrict__ E2, const int* __restrict__ rowptr,
                            const float* __restrict__ dinvG, const float* __restrict__ pred,
                            float* __restrict__ xaggH) {
    int n = blockIdx.x * 4 + (threadIdx.x >> 6);
    if (n >= NN) return;
    int lane = threadIdx.x & 63;
    int eo = lane >> 2, f = lane & 3;
    const uint2* gE = E2;                 // slot 0 = t 11
    const float* dv = dinvG + (size_t)11 * NN;
    int r0 = rowptr[(size_t)11 * RP + n], r1 = rowptr[(size_t)11 * RP + n + 1];
    float acc = 0.0f;
    for (int e = r0 + eo; e < r1; e += 16) {
        uint2 rc = gE[e];
        int s = rc.x;
        float nm = __uint_as_float(rc.y) * dv[s];
        if (f < 3) acc += nm * pred[(size_t)s * 3 + f];
    }
    acc += __shfl_xor(acc, 4);
    acc += __shfl_xor(acc, 8);
    acc += __shfl_xor(acc, 16);
    acc += __shfl_xor(acc, 32);
    if (lane < 3) {
        float dd = dv[n];
        xaggH[(size_t)n * FF + f] = dd * acc + dd * dd * pred[(size_t)n * 3 + f];
    }
}

// ---------------------------------------------------------------------------
// W: fold Wc into Wl_top -> BcatT[g][n=128][k=144] (f16, n-major for
// vectorized LDS fill), beff[g][128] (f32)
__global__ void weight_kernel(const float* Wc0, const float* bc0, const float* Wl0, const float* bl0,
                              const float* Wc1, const float* bc1, const float* Wl1, const float* bl1,
                              const float* Wc2, const float* bc2, const float* Wl2, const float* bl2,
                              _Float16* __restrict__ BcatT, float* __restrict__ beff) {
    __shared__ float WcS[FF][HH];
    int g = blockIdx.x;
    int n = threadIdx.x;  // 128
    const float* Wc = g == 0 ? Wc0 : (g == 1 ? Wc1 : Wc2);
    const float* bc = g == 0 ? bc0 : (g == 1 ? bc1 : bc2);
    const float* Wl = g == 0 ? Wl0 : (g == 1 ? Wl1 : Wl2);
    const float* bl = g == 0 ? bl0 : (g == 1 ? bl1 : bl2);
    for (int q = 0; q < FF; q++) WcS[q][n] = Wc[q * HH + n];
    __syncthreads();
    float acc[FF];
#pragma unroll
    for (int i = 0; i < FF; i++) acc[i] = 0.0f;
    float accb = 0.0f;
    for (int k = 0; k < HH; k++) {
        float wl = Wl[k * HH + n];
        accb += bc[k] * wl;
#pragma unroll
        for (int i = 0; i < FF; i++) acc[i] += WcS[i][k] * wl;
    }
    _Float16* row = BcatT + ((size_t)g * HH + n) * 144;
#pragma unroll
    for (int i = 0; i < FF; i++) row[i] = (_Float16)acc[i];
    for (int j = 0; j < HH; j++) row[16 + j] = (_Float16)Wl[(size_t)(HH + j) * HH + n];
    beff[g * HH + n] = bl[n] + accb;
}

// C1: hp[n][:] = m[n] ? h_state[n][:] : 0   (f16, 8 halves per thread)
__global__ void prep_hp(const _Float16* __restrict__ hstate, const unsigned char* __restrict__ m,
                        _Float16* __restrict__ hp) {
    int gid = blockIdx.x * 256 + threadIdx.x;  // NN*16 uint4s (3125 blocks exact)
    int n = gid >> 4;
    uint4 v = make_uint4(0, 0, 0, 0);
    if (m[n]) v = ((const uint4*)hstate)[gid];
    ((uint4*)hp)[gid] = v;
}

// ---------------------------------------------------------------------------
// CELL: fused z/r/h~ f16-MFMA GRU cell. 64 rows/block, 4 waves, K=144 (pad 160).
// h state is f16 end-to-end. hmask null -> h_prev = hstate; else gated.
// mcmask null -> always store; else conditional (in-place hstate update).
__launch_bounds__(256)
__global__ void cell_kernel(const float* __restrict__ xagg, const _Float16* __restrict__ hstate,
                            const _Float16* __restrict__ BcatT, const float* __restrict__ beff,
                            const unsigned char* __restrict__ hmask,
                            const unsigned char* __restrict__ mcmask,
                            _Float16* __restrict__ outh) {
    __shared__ _Float16 As[64 * BSTRH];    // 21504 B
    __shared__ _Float16 Bs[128 * BSTRH];   // 43008 B (one gate at a time; also rT scratch)
    const int tid = threadIdx.x;
    const int m0 = blockIdx.x * 64;
    const int lane = tid & 63;
    const int w = tid >> 6;
    const int mrow = lane & 15;
    const int quad = lane >> 4;

    // --- stage A: [xagg(16) | h_prev(128)] as f16, zero-pad k=144..159 ---
    {
        int row = tid >> 2, q = tid & 3;
        int g = m0 + row;
        float4 v = make_float4(0, 0, 0, 0);
        if (g < NN) v = *(const float4*)(xagg + (size_t)g * FF + 4 * q);
        _Float16* p = As + row * BSTRH + 4 * q;
        p[0] = (_Float16)v.x; p[1] = (_Float16)v.y; p[2] = (_Float16)v.z; p[3] = (_Float16)v.w;
        _Float16* pp = As + row * BSTRH + 144 + 4 * q;
        pp[0] = (_Float16)0; pp[1] = (_Float16)0; pp[2] = (_Float16)0; pp[3] = (_Float16)0;
    }
    for (int idx = tid; idx < 64 * 16; idx += 256) {   // h: 8 halves (uint4) each
        int row = idx >> 4, q = idx & 15;
        int g = m0 + row;
        uint4 v = make_uint4(0, 0, 0, 0);
        if (g < NN && (hmask == nullptr || hmask[g]))
            v = *(const uint4*)(hstate + (size_t)g * HH + 8 * q);
        *(uint4*)(As + row * BSTRH + 16 + 8 * q) = v;
    }

    const _Float16* Abase = As + (w * 16 + mrow) * BSTRH + quad * 8;
    const _Float16* Bbase = Bs + mrow * BSTRH + quad * 8;

    floatx4 zacc[8], racc[8];
#pragma unroll
    for (int c = 0; c < 8; c++)
#pragma unroll
        for (int i = 0; i < 4; i++) { zacc[c][i] = 0.0f; racc[c][i] = 0.0f; }

    // ---- gate z: vectorized B fill (BcatT row-major [n][144]) + pad ----
    for (int idx = tid; idx < 128 * 18; idx += 256) {
        int n = idx / 18, v = idx % 18;
        *(uint4*)(Bs + n * BSTRH + 8 * v) = *(const uint4*)(BcatT + (size_t)n * 144 + 8 * v);
    }
    for (int idx = tid; idx < 128 * 2; idx += 256)
        *(uint4*)(Bs + (idx >> 1) * BSTRH + 144 + 8 * (idx & 1)) = make_uint4(0, 0, 0, 0);
    __syncthreads();
    half8_t a_frag[5];
#pragma unroll
    for (int ks = 0; ks < 5; ks++) a_frag[ks] = *(const half8_t*)(Abase + ks * 32);
#pragma unroll
    for (int ks = 0; ks < 5; ks++)
#pragma unroll
        for (int c = 0; c < 8; c++) {
            half8_t b = *(const half8_t*)(Bbase + c * 16 * BSTRH + ks * 32);
            zacc[c] = __builtin_amdgcn_mfma_f32_16x16x32_f16(a_frag[ks], b, zacc[c], 0, 0, 0);
        }
    __syncthreads();
    // ---- gate r (pads still zero) ----
    for (int idx = tid; idx < 128 * 18; idx += 256) {
        int n = idx / 18, v = idx % 18;
        *(uint4*)(Bs + n * BSTRH + 8 * v) =
            *(const uint4*)(BcatT + (size_t)(128 + n) * 144 + 8 * v);
    }
    __syncthreads();
#pragma unroll
    for (int ks = 0; ks < 5; ks++)
#pragma unroll
        for (int c = 0; c < 8; c++) {
            half8_t b = *(const half8_t*)(Bbase + c * 16 * BSTRH + ks * 32);
            racc[c] = __builtin_amdgcn_mfma_f32_16x16x32_f16(a_frag[ks], b, racc[c], 0, 0, 0);
        }
    __syncthreads();
    // ---- r -> LDS (reuse Bs), then As.h *= r ----
    _Float16* rT = Bs;  // 64 x 130
#pragma unroll
    for (int c = 0; c < 8; c++)
#pragma unroll
        for (int i = 0; i < 4; i++) {
            int row = w * 16 + quad * 4 + i;
            int col = c * 16 + mrow;
            rT[row * 130 + col] = (_Float16)sigmoidf_(racc[c][i] + beff[HH + col]);
        }
    __syncthreads();
    for (int idx = tid; idx < 64 * 128; idx += 256) {
        int row = idx >> 7, col = idx & 127;
        As[row * BSTRH + 16 + col] = As[row * BSTRH + 16 + col] * rT[row * 130 + col];
    }
    __syncthreads();
    // ---- gate h~ (re-zero pads: rT clobbered rows 0..49's pad region) ----
    for (int idx = tid; idx < 128 * 18; idx += 256) {
        int n = idx / 18, v = idx % 18;
        *(uint4*)(Bs + n * BSTRH + 8 * v) =
            *(const uint4*)(BcatT + (size_t)(256 + n) * 144 + 8 * v);
    }
    for (int idx = tid; idx < 128 * 2; idx += 256)
        *(uint4*)(Bs + (idx >> 1) * BSTRH + 144 + 8 * (idx & 1)) = make_uint4(0, 0, 0, 0);
    __syncthreads();
    floatx4 hacc[8];
#pragma unroll
    for (int c = 0; c < 8; c++)
#pragma unroll
        for (int i = 0; i < 4; i++) hacc[c][i] = 0.0f;
#pragma unroll
    for (int ks = 0; ks < 5; ks++) {
        half8_t a = *(const half8_t*)(Abase + ks * 32);
#pragma unroll
        for (int c = 0; c < 8; c++) {
            half8_t b = *(const half8_t*)(Bbase + c * 16 * BSTRH + ks * 32);
            hacc[c] = __builtin_amdgcn_mfma_f32_16x16x32_f16(a, b, hacc[c], 0, 0, 0);
        }
    }
    // ---- epilogue: h_new = z*h_prev + (1-z)*tanh(h~), masked f16 store ----
#pragma unroll
    for (int c = 0; c < 8; c++) {
        int col = c * 16 + mrow;
        float bz = beff[col];
        float bh = beff[2 * HH + col];
#pragma unroll
        for (int i = 0; i < 4; i++) {
            int g = m0 + w * 16 + quad * 4 + i;
            if (g < NN) {
                float z = sigmoidf_(zacc[c][i] + bz);
                float ht = tanhf(hacc[c][i] + bh);
                float hpv = 0.0f;
                if (hmask == nullptr || hmask[g])
                    hpv = (float)hstate[(size_t)g * HH + col];
                float hn = z * hpv + (1.0f - z) * ht;
                if (mcmask == nullptr || mcmask[g])
                    outh[(size_t)g * HH + col] = (_Float16)hn;
            }
        }
    }
}

// C4: out[n][o] = h[n][:] . head_W[:,o] + head_b[o]; one wave per node
__global__ void head_kernel(const _Float16* __restrict__ hp, const float* __restrict__ headW,
                            const float* __restrict__ headb, float* __restrict__ out) {
    int node = (blockIdx.x * 256 + threadIdx.x) >> 6;
    int lane = threadIdx.x & 63;
    if (node >= NN) return;
    const _Float16* h = hp + (size_t)node * HH;
    float h0 = (float)h[lane], h1 = (float)h[64 + lane];
    float s0 = h0 * headW[lane * 3 + 0] + h1 * headW[(64 + lane) * 3 + 0];
    float s1 = h0 * headW[lane * 3 + 1] + h1 * headW[(64 + lane) * 3 + 1];
    float s2 = h0 * headW[lane * 3 + 2] + h1 * headW[(64 + lane) * 3 + 2];
#pragma unroll
    for (int off = 32; off > 0; off >>= 1) {
        s0 += __shfl_down(s0, off);
        s1 += __shfl_down(s1, off);
        s2 += __shfl_down(s2, off);
    }
    if (lane == 0) {
        out[(size_t)node * 3 + 0] = s0 + headb[0];
        out[(size_t)node * 3 + 1] = s1 + headb[1];
        out[(size_t)node * 3 + 2] = s2 + headb[2];
    }
}

extern "C" void kernel_launch(void* const* d_in, const int* in_sizes, int n_in,
                              void* d_out, int out_size, void* d_ws, size_t ws_size,
                              hipStream_t stream) {
    const float* x = (const float*)d_in[0];
    const int* ei = (const int*)d_in[1];
    const float* ea = (const float*)d_in[2];
    const void* mask = d_in[3];
    const float* Wc[3] = {(const float*)d_in[4], (const float*)d_in[8], (const float*)d_in[12]};
    const float* bc[3] = {(const float*)d_in[5], (const float*)d_in[9], (const float*)d_in[13]};
    const float* Wl[3] = {(const float*)d_in[6], (const float*)d_in[10], (const float*)d_in[14]};
    const float* bl[3] = {(const float*)d_in[7], (const float*)d_in[11], (const float*)d_in[15]};
    const float* headW = (const float*)d_in[16];
    const float* headb = (const float*)d_in[17];
    float* out = (float*)d_out;

    char* w = (char*)d_ws;
    auto alloc = [&](size_t bytes) {
        char* p = w;
        w += (bytes + 255) & ~(size_t)255;
        return p;
    };
    float* dinv = (float*)alloc((size_t)TT * NN * 4);
    float* xaggA = (float*)alloc((size_t)TT * NN * FF * 4);
    float* xaggH = (float*)alloc((size_t)NN * FF * 4);
    int* chunkHist = (int*)alloc((size_t)TT * NBINS * NCH * 4);
    int* rowptr = (int*)alloc((size_t)TT * RP * 4);
    uint2* E2 = (uint2*)alloc((size_t)TT * EE * 8);   // packed edge records, 12 slots
    _Float16* BcatT = (_Float16*)alloc((size_t)3 * HH * 144 * 2);
    float* beff = (float*)alloc(3 * HH * 4);
    unsigned char* hm = (unsigned char*)alloc((size_t)TT * NN);
    unsigned char* mc = (unsigned char*)alloc((size_t)TT * NN);
    int* flag = (int*)alloc(64);

    // f16 hidden state aliases dead E2 slots after gathers (slot 0 = t 11
    // survives for the horizon). NN*HH*2 bytes = 12.8 MB = exactly one slot.
    _Float16* hstate = (_Float16*)(E2 + (size_t)1 * EE);  // slot 1
    _Float16* hph    = (_Float16*)(E2 + (size_t)2 * EE);  // slot 2

    detect_mask<<<1, 256, 0, stream>>>((const unsigned char*)mask, flag);
    build_masks<<<(NN + 255) / 256, 256, 0, stream>>>(mask, flag, hm, mc);

    hist_kernel<<<dim3(NCH, TT), 256, 0, stream>>>(ei, chunkHist);
    scan_kernel<<<TT, 1024, 0, stream>>>(chunkHist);
    scatter_kernel<<<dim3(NCH, TT), 256, 0, stream>>>(ei, ea, chunkHist, E2);
    sortbin_kernel<<<dim3(NBINS, TT), 256, 0, stream>>>(E2, chunkHist, rowptr, dinv);
    gather_csr<<<dim3((NN + 3) / 4, TT), 256, 0, stream>>>(E2, rowptr, dinv, x, xaggA);

    weight_kernel<<<3, 128, 0, stream>>>(Wc[0], bc[0], Wl[0], bl[0],
                                         Wc[1], bc[1], Wl[1], bl[1],
                                         Wc[2], bc[2], Wl[2], bl[2], BcatT, beff);

    // hstate aliases E2 slot 1 -> zero only after gathers consumed it
    hipMemsetAsync(hstate, 0, (size_t)NN * HH * 2, stream);

    // recurrent cells t = 0..11 (in-place hstate update, mask-gated)
    for (int t = 0; t < TT; t++) {
        cell_kernel<<<CGB, 256, 0, stream>>>(xaggA + (size_t)t * NN * FF, hstate, BcatT, beff,
                                             hm + (size_t)t * NN, mc + (size_t)t * NN, hstate);
    }

    // horizon: hph = mask[T-1] ? h_state : 0, then unconditional GRU chain
    prep_hp<<<NN * 16 / 256, 256, 0, stream>>>(hstate, mc + (size_t)11 * NN, hph);
    hipMemcpyAsync(xaggH, xaggA + (size_t)11 * NN * FF, (size_t)NN * FF * 4,
                   hipMemcpyDeviceToDevice, stream);

    for (int k = 0; k < 6; k++) {
        const float* xa = (k == 0) ? (xaggA + (size_t)11 * NN * FF) : xaggH;
        cell_kernel<<<CGB, 256, 0, stream>>>(xa, hph, BcatT, beff, nullptr, nullptr, hph);
        head_kernel<<<NN * 64 / 256, 256, 0, stream>>>(hph, headW, headb, out + (size_t)k * NN * 3);
        if (k < 5) {
            gather3_csr<<<(NN + 3) / 4, 256, 0, stream>>>(E2, rowptr, dinv,
                                                          out + (size_t)k * NN * 3, xaggH);
        }
    }
}

// Round 5
// 2459.863 us; speedup vs baseline: 8.4234x; 1.1314x over previous
//
#include <hip/hip_runtime.h>
#include <math.h>

#define NN 50000
#define TT 12
#define EE 1600000
#define FF 16
#define HH 128
#define CHK 4096     // edges per chunk (level-1 histogram / scatter staging)
#define NCH 391      // ceil(EE/CHK)
#define BKT 128      // nodes per bin
#define NBINS 391    // ceil(NN/BKT) -> covers 50048
#define CAP 6144     // max edges per bin segment (mean 4096, sigma 64)
#define RP 50016     // rowptr stride per t (>= NN+1)
#define CGB 782      // ceil(NN/64) cell blocks
#define BSTRH 168    // LDS K-stride in halves (144 padded to 168; 168 gives 2-way-free banking)

typedef _Float16 half8_t __attribute__((ext_vector_type(8)));
typedef float floatx4 __attribute__((ext_vector_type(4)));

__device__ __forceinline__ float sigmoidf_(float x) { return 1.0f / (1.0f + expf(-x)); }
__device__ __forceinline__ float h16_to_f(unsigned short u) {
    _Float16 h; __builtin_memcpy(&h, &u, 2); return (float)h;
}
__device__ __forceinline__ unsigned short f_to_h16(float f) {
    _Float16 h = (_Float16)f; unsigned short u; __builtin_memcpy(&u, &h, 2); return u;
}

// ---------------------------------------------------------------------------
// P0: detect mask dtype from byte pattern (uint8 / int32 / float32).
__global__ void detect_mask(const unsigned char* __restrict__ m, int* __restrict__ flag) {
    __shared__ int cnt[2];
    if (threadIdx.x < 2) cnt[threadIdx.x] = 0;
    __syncthreads();
    int a = 0, b = 0;
    for (int base = 0; base < 4096; base += 256) {
        int idx = base + threadIdx.x;
        unsigned char v = m[idx];
        int r = idx & 3;
        if (v) { if (r == 0) a++; else if (r == 1) b++; }
    }
    atomicAdd(&cnt[0], a);
    atomicAdd(&cnt[1], b);
    __syncthreads();
    if (threadIdx.x == 0) flag[0] = cnt[1] > 0 ? 0 : (cnt[0] > 0 ? 1 : 2);
}

// P1: hm[t][n] = mask & seen-before, mc[t][n] = mask
__global__ void build_masks(const void* __restrict__ mask, const int* __restrict__ flag,
                            unsigned char* __restrict__ hm, unsigned char* __restrict__ mc) {
    int n = blockIdx.x * 256 + threadIdx.x;
    if (n >= NN) return;
    int mode = flag[0];
    bool seen = false;
    for (int t = 0; t < TT; t++) {
        int idx = t * NN + n;
        bool m;
        if (mode == 0)      m = ((const unsigned char*)mask)[idx] != 0;
        else if (mode == 1) m = ((const int*)mask)[idx] != 0;
        else                m = ((const float*)mask)[idx] != 0.0f;
        hm[idx] = (m && seen) ? 1 : 0;
        mc[idx] = m ? 1 : 0;
        seen = seen || m;
    }
}

// ---------------------------------------------------------------------------
// S1: per-chunk histogram of dst bins (bin = dst>>7). layout [t][bin][chunk]
__global__ void hist_kernel(const int* __restrict__ ei, int* __restrict__ chunkHist) {
    __shared__ int h[NBINS + 1];
    int c = blockIdx.x, t = blockIdx.y, tid = threadIdx.x;
    for (int i = tid; i < NBINS; i += 256) h[i] = 0;
    __syncthreads();
    const int* dstp = ei + (size_t)(2 * t + 1) * EE;
    int e0 = c * CHK;
    for (int i = tid; i < CHK; i += 256) {
        int e = e0 + i;
        if (e < EE) atomicAdd(&h[dstp[e] >> 7], 1);
    }
    __syncthreads();
    for (int i = tid; i < NBINS; i += 256)
        chunkHist[((size_t)t * NBINS + i) * NCH + c] = h[i];
}

// S2: in-place exclusive scan of each t's [NBINS*NCH] array
__global__ void scan_kernel(int* __restrict__ buf) {
    __shared__ int ps[1024];
    const int L = NBINS * NCH;   // 152881
    const int PER = 150;         // 1024*150 >= L
    int t = blockIdx.x, tid = threadIdx.x;
    int* a = buf + (size_t)t * L;
    int i0 = tid * PER, i1 = min(i0 + PER, L);
    int s = 0;
    for (int i = i0; i < i1; i++) s += a[i];
    ps[tid] = s;
    __syncthreads();
    for (int off = 1; off < 1024; off <<= 1) {
        int v = (tid >= off) ? ps[tid - off] : 0;
        __syncthreads();
        ps[tid] += v;
        __syncthreads();
    }
    int base = (tid == 0) ? 0 : ps[tid - 1];
    for (int i = i0; i < i1; i++) { int v = a[i]; a[i] = base; base += v; }
}

// S3: LDS-staged scatter into bin-sorted order (batch of 6 t's).
// Record: uint2{src|dst<<16, w_f32}. Coalesced segment write-out.
__launch_bounds__(256)
__global__ void scatter_kernel(const int* __restrict__ ei, const float* __restrict__ ea,
                               const int* __restrict__ chunkOff, uint2* __restrict__ E2,
                               int batch) {
    __shared__ uint2 sorted[CHK];          // 32 KB
    __shared__ int cnt[NBINS];
    __shared__ int sA[NBINS], sB[NBINS];
    __shared__ int start[NBINS], gbase[NBINS];
    int c = blockIdx.x, y = blockIdx.y, tid = threadIdx.x;
    int t = batch * 6 + y;
    for (int i = tid; i < NBINS; i += 256) {
        cnt[i] = 0;
        gbase[i] = chunkOff[((size_t)t * NBINS + i) * NCH + c];
    }
    __syncthreads();
    const int* srcp = ei + (size_t)(2 * t) * EE;
    const int* dstp = ei + (size_t)(2 * t + 1) * EE;
    const float* wp = ea + (size_t)t * EE;
    int e0 = c * CHK;
    int m = min(CHK, EE - e0);
    uint2 rec[16];
    int rank[16];
#pragma unroll
    for (int k = 0; k < 16; k++) {
        int i = k * 256 + tid;
        rank[k] = -1;
        if (i < m) {
            int e = e0 + i;
            unsigned int s = (unsigned int)srcp[e];
            unsigned int d = (unsigned int)dstp[e];
            float wv = wp[e];
            rec[k].x = s | (d << 16);
            rec[k].y = __float_as_uint(wv);
            rank[k] = atomicAdd(&cnt[d >> 7], 1);
        }
    }
    __syncthreads();
    for (int i = tid; i < NBINS; i += 256) sA[i] = cnt[i];
    __syncthreads();
    int pp = 0;
    for (int off = 1; off < NBINS; off <<= 1) {
        if (pp == 0) {
            for (int i = tid; i < NBINS; i += 256)
                sB[i] = (i >= off) ? sA[i] + sA[i - off] : sA[i];
        } else {
            for (int i = tid; i < NBINS; i += 256)
                sA[i] = (i >= off) ? sB[i] + sB[i - off] : sB[i];
        }
        pp ^= 1;
        __syncthreads();
    }
    const int* inc = pp ? sB : sA;
    for (int i = tid; i < NBINS; i += 256) start[i] = inc[i] - cnt[i];
    __syncthreads();
#pragma unroll
    for (int k = 0; k < 16; k++) {
        if (rank[k] >= 0) {
            int b = rec[k].x >> 23;
            sorted[start[b] + rank[k]] = rec[k];
        }
    }
    __syncthreads();
    uint2* outp = E2 + (size_t)y * EE;
    for (int i = tid; i < m; i += 256) {
        uint2 r = sorted[i];
        int b = r.x >> 23;
        outp[gbase[b] + (i - start[b])] = r;
    }
}

// S4: per-bin counting sort -> compact CSR records (src u16 | w'=w*dinv[d] f16)
// + rowptr + dinv. Reads uint2 staging E2, writes 4B records to E1.
__launch_bounds__(256)
__global__ void sortbin_kernel(const uint2* __restrict__ E2, const int* __restrict__ chunkHist,
                               unsigned int* __restrict__ E1, int* __restrict__ rowptr,
                               float* __restrict__ dinvG, int batch) {
    __shared__ uint2 es[CAP];   // 48 KB
    __shared__ int cnt[BKT];
    __shared__ float wsm[BKT];
    __shared__ int cur[BKT];
    int b = blockIdx.x, y = blockIdx.y, tid = threadIdx.x;
    int t = batch * 6 + y;
    const uint2* gE = E2 + (size_t)y * EE;
    unsigned int* oE = E1 + (size_t)t * EE;
    const int* off = chunkHist + (size_t)t * NBINS * NCH;
    int e0 = off[b * NCH];
    int e1 = (b == NBINS - 1) ? EE : off[(b + 1) * NCH];
    int seg = e1 - e0;
    for (int i = tid; i < seg; i += 256) es[i] = gE[e0 + i];
    if (tid < BKT) { cnt[tid] = 0; wsm[tid] = 0.0f; }
    __syncthreads();
    for (int i = tid; i < seg; i += 256) {
        int dl = (es[i].x >> 16) & 127;
        atomicAdd(&cnt[dl], 1);
        atomicAdd(&wsm[dl], __uint_as_float(es[i].y));
    }
    __syncthreads();
    int ogv = (tid < BKT) ? cnt[tid] : 0;
    for (int o = 1; o < BKT; o <<= 1) {
        int u = (tid < BKT && tid >= o) ? cnt[tid - o] : 0;
        __syncthreads();
        if (tid < BKT) cnt[tid] += u;
        __syncthreads();
    }
    if (tid < BKT) {
        int exc = cnt[tid] - ogv;
        cur[tid] = exc;
        float dv = rsqrtf(1.0f + wsm[tid]);
        wsm[tid] = dv;   // reuse as dinv-local
        int node = b * BKT + tid;
        if (node <= NN) {
            rowptr[(size_t)t * RP + node] = e0 + exc;
            if (node < NN) dinvG[(size_t)t * NN + node] = dv;
        }
    }
    __syncthreads();
    for (int i = tid; i < seg; i += 256) {
        uint2 p = es[i];
        int dl = (p.x >> 16) & 127;
        int pos = atomicAdd(&cur[dl], 1);
        float wv = __uint_as_float(p.y) * wsm[dl];
        oE[e0 + pos] = (p.x & 0xFFFF) | ((unsigned int)f_to_h16(wv) << 16);
    }
}

// S4b: xs[t][n][f] = (f16)(dinv[t][n] * x[t][n][f])
__global__ void xs_kernel(const float* __restrict__ x, const float* __restrict__ dinvG,
                          _Float16* __restrict__ xs16) {
    int gid = blockIdx.x * 256 + threadIdx.x;   // TT*NN*4 float4 groups (exact: 9375 blocks)
    int tn = gid >> 2;
    float dd = dinvG[tn];
    float4 v = ((const float4*)x)[gid];
    _Float16 h[4] = {(_Float16)(dd * v.x), (_Float16)(dd * v.y),
                     (_Float16)(dd * v.z), (_Float16)(dd * v.w)};
    uint2 o;
    __builtin_memcpy(&o, h, 8);
    ((uint2*)xs16)[gid] = o;
}

// S5: CSR gather: wave per (t,node). 8 edges x 8 feature-pairs per iteration.
// xagg[t][n][f] = sum_e w'_e * xs[s][f] + dinv[n]*xs[n][f]   (all f16 in, f32 acc)
__global__ void gather_csr(const unsigned int* __restrict__ E1, const int* __restrict__ rowptr,
                           const float* __restrict__ dinvG, const _Float16* __restrict__ xs16,
                           _Float16* __restrict__ xagg16) {
    int t = blockIdx.y;
    int n = blockIdx.x * 4 + (threadIdx.x >> 6);
    if (n >= NN) return;
    int lane = threadIdx.x & 63;
    int eo = lane >> 3, fp = lane & 7;
    const unsigned int* gE = E1 + (size_t)t * EE;
    const _Float16* xs = xs16 + (size_t)t * NN * FF;
    int r0 = rowptr[(size_t)t * RP + n], r1 = rowptr[(size_t)t * RP + n + 1];
    float a0 = 0.0f, a1 = 0.0f;
    for (int e = r0 + eo; e < r1; e += 8) {
        unsigned int rec = gE[e];
        float wv = h16_to_f((unsigned short)(rec >> 16));
        unsigned int xp = *(const unsigned int*)(xs + (size_t)(rec & 0xFFFF) * FF + 2 * fp);
        a0 += wv * h16_to_f((unsigned short)(xp & 0xFFFF));
        a1 += wv * h16_to_f((unsigned short)(xp >> 16));
    }
    a0 += __shfl_xor(a0, 8);  a1 += __shfl_xor(a1, 8);
    a0 += __shfl_xor(a0, 16); a1 += __shfl_xor(a1, 16);
    a0 += __shfl_xor(a0, 32); a1 += __shfl_xor(a1, 32);
    if (eo == 0) {
        float dd = dinvG[(size_t)t * NN + n];
        unsigned int xp = *(const unsigned int*)(xs + (size_t)n * FF + 2 * fp);
        float o0 = a0 + dd * h16_to_f((unsigned short)(xp & 0xFFFF));
        float o1 = a1 + dd * h16_to_f((unsigned short)(xp >> 16));
        unsigned int pack = (unsigned int)f_to_h16(o0) | ((unsigned int)f_to_h16(o1) << 16);
        ((unsigned int*)(xagg16 + ((size_t)t * NN + n) * FF))[fp] = pack;
    }
}

// S6 (horizon): 3-feature CSR re-aggregation of predsc (= dinv*pred) over t=11.
__global__ void gather3_csr(const unsigned int* __restrict__ E1, const int* __restrict__ rowptr,
                            const float* __restrict__ dinvG, const float* __restrict__ predsc,
                            _Float16* __restrict__ xaggH16) {
    int n = blockIdx.x * 4 + (threadIdx.x >> 6);
    if (n >= NN) return;
    int lane = threadIdx.x & 63;
    int eo = lane >> 2, f = lane & 3;
    const unsigned int* gE = E1 + (size_t)11 * EE;
    const float* dv = dinvG + (size_t)11 * NN;
    int r0 = rowptr[(size_t)11 * RP + n], r1 = rowptr[(size_t)11 * RP + n + 1];
    float acc = 0.0f;
    for (int e = r0 + eo; e < r1; e += 16) {
        unsigned int rec = gE[e];
        float wv = h16_to_f((unsigned short)(rec >> 16));
        if (f < 3) acc += wv * predsc[(size_t)(rec & 0xFFFF) * 4 + f];
    }
    acc += __shfl_xor(acc, 4);
    acc += __shfl_xor(acc, 8);
    acc += __shfl_xor(acc, 16);
    acc += __shfl_xor(acc, 32);
    if (lane < 3) {
        float res = acc + dv[n] * predsc[(size_t)n * 4 + f];
        xaggH16[(size_t)n * FF + f] = (_Float16)res;
    }
}

// ---------------------------------------------------------------------------
// W: fold Wc into Wl_top -> BcatT[g][n=128][k=144] (f16), beff[g][128] (f32)
__global__ void weight_kernel(const float* Wc0, const float* bc0, const float* Wl0, const float* bl0,
                              const float* Wc1, const float* bc1, const float* Wl1, const float* bl1,
                              const float* Wc2, const float* bc2, const float* Wl2, const float* bl2,
                              _Float16* __restrict__ BcatT, float* __restrict__ beff) {
    __shared__ float WcS[FF][HH];
    int g = blockIdx.x;
    int n = threadIdx.x;  // 128
    const float* Wc = g == 0 ? Wc0 : (g == 1 ? Wc1 : Wc2);
    const float* bc = g == 0 ? bc0 : (g == 1 ? bc1 : bc2);
    const float* Wl = g == 0 ? Wl0 : (g == 1 ? Wl1 : Wl2);
    const float* bl = g == 0 ? bl0 : (g == 1 ? bl1 : bl2);
    for (int q = 0; q < FF; q++) WcS[q][n] = Wc[q * HH + n];
    __syncthreads();
    float acc[FF];
#pragma unroll
    for (int i = 0; i < FF; i++) acc[i] = 0.0f;
    float accb = 0.0f;
    for (int k = 0; k < HH; k++) {
        float wl = Wl[k * HH + n];
        accb += bc[k] * wl;
#pragma unroll
        for (int i = 0; i < FF; i++) acc[i] += WcS[i][k] * wl;
    }
    _Float16* row = BcatT + ((size_t)g * HH + n) * 144;
#pragma unroll
    for (int i = 0; i < FF; i++) row[i] = (_Float16)acc[i];
    for (int j = 0; j < HH; j++) row[16 + j] = (_Float16)Wl[(size_t)(HH + j) * HH + n];
    beff[g * HH + n] = bl[n] + accb;
}

// C1: hp[n][:] = m[n] ? h_state[n][:] : 0   (f16, uint4 per thread)
__global__ void prep_hp(const _Float16* __restrict__ hstate, const unsigned char* __restrict__ m,
                        _Float16* __restrict__ hp) {
    int gid = blockIdx.x * 256 + threadIdx.x;  // NN*16 uint4s (3125 blocks exact)
    int n = gid >> 4;
    uint4 v = make_uint4(0, 0, 0, 0);
    if (m[n]) v = ((const uint4*)hstate)[gid];
    ((uint4*)hp)[gid] = v;
}

// ---------------------------------------------------------------------------
// CELL: fused z/r/h~ f16-MFMA GRU cell. 64 rows/block, 4 waves, K=144 (pad 168).
__launch_bounds__(256)
__global__ void cell_kernel(const _Float16* __restrict__ xagg16, const _Float16* __restrict__ hstate,
                            const _Float16* __restrict__ BcatT, const float* __restrict__ beff,
                            const unsigned char* __restrict__ hmask,
                            const unsigned char* __restrict__ mcmask,
                            _Float16* __restrict__ outh) {
    __shared__ _Float16 As[64 * BSTRH];    // 21504 B
    __shared__ _Float16 Bs[128 * BSTRH];   // 43008 B (one gate at a time; also rT scratch)
    const int tid = threadIdx.x;
    const int m0 = blockIdx.x * 64;
    const int lane = tid & 63;
    const int w = tid >> 6;
    const int mrow = lane & 15;
    const int quad = lane >> 4;

    // --- stage A: [xagg(16) | h_prev(128)] f16, zero-pad k=144..167 ---
    {
        int row = tid >> 2, q = tid & 3;
        int g = m0 + row;
        uint2 v = make_uint2(0, 0);
        if (g < NN) v = *(const uint2*)(xagg16 + (size_t)g * FF + 4 * q);
        *(uint2*)(As + row * BSTRH + 4 * q) = v;
    }
    for (int idx = tid; idx < 64 * 3; idx += 256) {
        int row = idx / 3, v3 = idx % 3;
        *(uint4*)(As + row * BSTRH + 144 + 8 * v3) = make_uint4(0, 0, 0, 0);
    }
    for (int idx = tid; idx < 64 * 16; idx += 256) {   // h: 8 halves (uint4) each
        int row = idx >> 4, q = idx & 15;
        int g = m0 + row;
        uint4 v = make_uint4(0, 0, 0, 0);
        if (g < NN && (hmask == nullptr || hmask[g]))
            v = *(const uint4*)(hstate + (size_t)g * HH + 8 * q);
        *(uint4*)(As + row * BSTRH + 16 + 8 * q) = v;
    }

    const _Float16* Abase = As + (w * 16 + mrow) * BSTRH + quad * 8;
    const _Float16* Bbase = Bs + mrow * BSTRH + quad * 8;

    floatx4 zacc[8], racc[8];
#pragma unroll
    for (int c = 0; c < 8; c++)
#pragma unroll
        for (int i = 0; i < 4; i++) { zacc[c][i] = 0.0f; racc[c][i] = 0.0f; }

    // ---- gate z: B fill (21 uint4/row: 18 data + 3 zero pad) ----
    for (int idx = tid; idx < 128 * 21; idx += 256) {
        int n = idx / 21, v = idx % 21;
        uint4 val = make_uint4(0, 0, 0, 0);
        if (v < 18) val = *(const uint4*)(BcatT + (size_t)n * 144 + 8 * v);
        *(uint4*)(Bs + n * BSTRH + 8 * v) = val;
    }
    __syncthreads();
    half8_t a_frag[5];
#pragma unroll
    for (int ks = 0; ks < 5; ks++) a_frag[ks] = *(const half8_t*)(Abase + ks * 32);
#pragma unroll
    for (int ks = 0; ks < 5; ks++)
#pragma unroll
        for (int c = 0; c < 8; c++) {
            half8_t b = *(const half8_t*)(Bbase + c * 16 * BSTRH + ks * 32);
            zacc[c] = __builtin_amdgcn_mfma_f32_16x16x32_f16(a_frag[ks], b, zacc[c], 0, 0, 0);
        }
    __syncthreads();
    // ---- gate r ----
    for (int idx = tid; idx < 128 * 21; idx += 256) {
        int n = idx / 21, v = idx % 21;
        uint4 val = make_uint4(0, 0, 0, 0);
        if (v < 18) val = *(const uint4*)(BcatT + (size_t)(128 + n) * 144 + 8 * v);
        *(uint4*)(Bs + n * BSTRH + 8 * v) = val;
    }
    __syncthreads();
#pragma unroll
    for (int ks = 0; ks < 5; ks++)
#pragma unroll
        for (int c = 0; c < 8; c++) {
            half8_t b = *(const half8_t*)(Bbase + c * 16 * BSTRH + ks * 32);
            racc[c] = __builtin_amdgcn_mfma_f32_16x16x32_f16(a_frag[ks], b, racc[c], 0, 0, 0);
        }
    __syncthreads();
    // ---- h_prev fragments from LDS (pre-scale), then r -> LDS, As.h *= r ----
    _Float16 hprev[32];
#pragma unroll
    for (int c = 0; c < 8; c++)
#pragma unroll
        for (int i = 0; i < 4; i++) {
            int row = w * 16 + quad * 4 + i;
            hprev[c * 4 + i] = As[row * BSTRH + 16 + c * 16 + mrow];
        }
    _Float16* rT = Bs;  // 64 x 130
#pragma unroll
    for (int c = 0; c < 8; c++)
#pragma unroll
        for (int i = 0; i < 4; i++) {
            int row = w * 16 + quad * 4 + i;
            int col = c * 16 + mrow;
            rT[row * 130 + col] = (_Float16)sigmoidf_(racc[c][i] + beff[HH + col]);
        }
    __syncthreads();
    for (int idx = tid; idx < 64 * 128; idx += 256) {
        int row = idx >> 7, col = idx & 127;
        As[row * BSTRH + 16 + col] = As[row * BSTRH + 16 + col] * rT[row * 130 + col];
    }
    __syncthreads();
    // ---- gate h~ (full fill incl pads: rT clobbered them) ----
    for (int idx = tid; idx < 128 * 21; idx += 256) {
        int n = idx / 21, v = idx % 21;
        uint4 val = make_uint4(0, 0, 0, 0);
        if (v < 18) val = *(const uint4*)(BcatT + (size_t)(256 + n) * 144 + 8 * v);
        *(uint4*)(Bs + n * BSTRH + 8 * v) = val;
    }
    __syncthreads();
    floatx4 hacc[8];
#pragma unroll
    for (int c = 0; c < 8; c++)
#pragma unroll
        for (int i = 0; i < 4; i++) hacc[c][i] = 0.0f;
#pragma unroll
    for (int ks = 0; ks < 5; ks++) {
        half8_t a = *(const half8_t*)(Abase + ks * 32);
#pragma unroll
        for (int c = 0; c < 8; c++) {
            half8_t b = *(const half8_t*)(Bbase + c * 16 * BSTRH + ks * 32);
            hacc[c] = __builtin_amdgcn_mfma_f32_16x16x32_f16(a, b, hacc[c], 0, 0, 0);
        }
    }
    // ---- epilogue: h_new = z*h_prev + (1-z)*tanh(h~), masked f16 store ----
#pragma unroll
    for (int c = 0; c < 8; c++) {
        int col = c * 16 + mrow;
        float bz = beff[col];
        float bh = beff[2 * HH + col];
#pragma unroll
        for (int i = 0; i < 4; i++) {
            int g = m0 + w * 16 + quad * 4 + i;
            if (g < NN) {
                float z = sigmoidf_(zacc[c][i] + bz);
                float ht = tanhf(hacc[c][i] + bh);
                float hpv = (float)hprev[c * 4 + i];
                float hn = z * hpv + (1.0f - z) * ht;
                if (mcmask == nullptr || mcmask[g])
                    outh[(size_t)g * HH + col] = (_Float16)hn;
            }
        }
    }
}

// C4: out[n][o] = h . head_W[:,o] + head_b[o]; also predsc[n][o] = dinv11[n]*out
__global__ void head_kernel(const _Float16* __restrict__ hp, const float* __restrict__ headW,
                            const float* __restrict__ headb, const float* __restrict__ dinv11,
                            float* __restrict__ out, float* __restrict__ predsc) {
    int node = (blockIdx.x * 256 + threadIdx.x) >> 6;
    int lane = threadIdx.x & 63;
    if (node >= NN) return;
    const _Float16* h = hp + (size_t)node * HH;
    float h0 = (float)h[lane], h1 = (float)h[64 + lane];
    float s0 = h0 * headW[lane * 3 + 0] + h1 * headW[(64 + lane) * 3 + 0];
    float s1 = h0 * headW[lane * 3 + 1] + h1 * headW[(64 + lane) * 3 + 1];
    float s2 = h0 * headW[lane * 3 + 2] + h1 * headW[(64 + lane) * 3 + 2];
#pragma unroll
    for (int off = 32; off > 0; off >>= 1) {
        s0 += __shfl_down(s0, off);
        s1 += __shfl_down(s1, off);
        s2 += __shfl_down(s2, off);
    }
    if (lane == 0) {
        float o0 = s0 + headb[0], o1 = s1 + headb[1], o2 = s2 + headb[2];
        out[(size_t)node * 3 + 0] = o0;
        out[(size_t)node * 3 + 1] = o1;
        out[(size_t)node * 3 + 2] = o2;
        float dd = dinv11[node];
        predsc[(size_t)node * 4 + 0] = dd * o0;
        predsc[(size_t)node * 4 + 1] = dd * o1;
        predsc[(size_t)node * 4 + 2] = dd * o2;
    }
}

extern "C" void kernel_launch(void* const* d_in, const int* in_sizes, int n_in,
                              void* d_out, int out_size, void* d_ws, size_t ws_size,
                              hipStream_t stream) {
    const float* x = (const float*)d_in[0];
    const int* ei = (const int*)d_in[1];
    const float* ea = (const float*)d_in[2];
    const void* mask = d_in[3];
    const float* Wc[3] = {(const float*)d_in[4], (const float*)d_in[8], (const float*)d_in[12]};
    const float* bc[3] = {(const float*)d_in[5], (const float*)d_in[9], (const float*)d_in[13]};
    const float* Wl[3] = {(const float*)d_in[6], (const float*)d_in[10], (const float*)d_in[14]};
    const float* bl[3] = {(const float*)d_in[7], (const float*)d_in[11], (const float*)d_in[15]};
    const float* headW = (const float*)d_in[16];
    const float* headb = (const float*)d_in[17];
    float* out = (float*)d_out;

    char* w = (char*)d_ws;
    auto alloc = [&](size_t bytes) {
        char* p = w;
        w += (bytes + 255) & ~(size_t)255;
        return p;
    };
    float* dinv = (float*)alloc((size_t)TT * NN * 4);
    _Float16* xagg16 = (_Float16*)alloc((size_t)TT * NN * FF * 2);
    _Float16* xaggH16 = (_Float16*)alloc((size_t)NN * FF * 2);
    _Float16* xs16 = (_Float16*)alloc((size_t)TT * NN * FF * 2);
    int* chunkHist = (int*)alloc((size_t)TT * NBINS * NCH * 4);
    int* rowptr = (int*)alloc((size_t)TT * RP * 4);
    unsigned int* E1 = (unsigned int*)alloc((size_t)TT * EE * 4);  // compact CSR records
    uint2* E2 = (uint2*)alloc((size_t)6 * EE * 8);                 // staging, 6 slots (2 batches)
    _Float16* BcatT = (_Float16*)alloc((size_t)3 * HH * 144 * 2);
    float* beff = (float*)alloc(3 * HH * 4);
    float* predsc = (float*)alloc((size_t)NN * 4 * 4);
    unsigned char* hm = (unsigned char*)alloc((size_t)TT * NN);
    unsigned char* mc = (unsigned char*)alloc((size_t)TT * NN);
    int* flag = (int*)alloc(64);

    // f16 hidden states alias the E2 staging area (dead after sortbin batches).
    _Float16* hstate = (_Float16*)E2;                          // 12.8 MB
    _Float16* hph = (_Float16*)((char*)E2 + (size_t)NN * HH * 2);

    detect_mask<<<1, 256, 0, stream>>>((const unsigned char*)mask, flag);
    build_masks<<<(NN + 255) / 256, 256, 0, stream>>>(mask, flag, hm, mc);

    hist_kernel<<<dim3(NCH, TT), 256, 0, stream>>>(ei, chunkHist);
    scan_kernel<<<TT, 1024, 0, stream>>>(chunkHist);
    for (int b = 0; b < 2; b++) {
        scatter_kernel<<<dim3(NCH, 6), 256, 0, stream>>>(ei, ea, chunkHist, E2, b);
        sortbin_kernel<<<dim3(NBINS, 6), 256, 0, stream>>>(E2, chunkHist, E1, rowptr, dinv, b);
    }
    xs_kernel<<<TT * NN * 4 / 256, 256, 0, stream>>>(x, dinv, xs16);
    gather_csr<<<dim3((NN + 3) / 4, TT), 256, 0, stream>>>(E1, rowptr, dinv, xs16, xagg16);

    weight_kernel<<<3, 128, 0, stream>>>(Wc[0], bc[0], Wl[0], bl[0],
                                         Wc[1], bc[1], Wl[1], bl[1],
                                         Wc[2], bc[2], Wl[2], bl[2], BcatT, beff);

    // hstate aliases E2 -> zero only after sortbin batches consumed it
    hipMemsetAsync(hstate, 0, (size_t)NN * HH * 2, stream);

    // recurrent cells t = 0..11 (in-place hstate update, mask-gated)
    for (int t = 0; t < TT; t++) {
        cell_kernel<<<CGB, 256, 0, stream>>>(xagg16 + (size_t)t * NN * FF, hstate, BcatT, beff,
                                             hm + (size_t)t * NN, mc + (size_t)t * NN, hstate);
    }

    // horizon: hph = mask[T-1] ? h_state : 0, then unconditional GRU chain
    prep_hp<<<NN * 16 / 256, 256, 0, stream>>>(hstate, mc + (size_t)11 * NN, hph);
    hipMemcpyAsync(xaggH16, xagg16 + (size_t)11 * NN * FF, (size_t)NN * FF * 2,
                   hipMemcpyDeviceToDevice, stream);

    for (int k = 0; k < 6; k++) {
        const _Float16* xa = (k == 0) ? (xagg16 + (size_t)11 * NN * FF) : xaggH16;
        cell_kernel<<<CGB, 256, 0, stream>>>(xa, hph, BcatT, beff, nullptr, nullptr, hph);
        head_kernel<<<NN * 64 / 256, 256, 0, stream>>>(hph, headW, headb, dinv + (size_t)11 * NN,
                                                       out + (size_t)k * NN * 3, predsc);
        if (k < 5) {
            gather3_csr<<<(NN + 3) / 4, 256, 0, stream>>>(E1, rowptr, dinv, predsc, xaggH16);
        }
    }
}